// Round 11
// baseline (2120.208 us; speedup 1.0000x reference)
//
#include <hip/hip_runtime.h>
#include <math.h>

// GraphNet: 2x EdgeConv (E=800k, F=H=64) + BN folded/commuted + pooling.
// R11: conv1's pass2 de-scattered. pass2w streams the h1a spill, does GEMM-b
// + stats1b, and writes h1b LINEARLY in-place over the consumed h1a region
// (no ep reads, no shuffles, no atomics). pass2m pulls per-node max over the
// CSR row range, applies BN1b, writes x1b (absorbs k_x1). conv2 stays pull
// (R10 pass3p, proven fast). pass1s unchanged (890us, gather+GEMM-a+spill).
// ws layout byte-identical to R10's proven 237.7MB.

typedef unsigned short u16;
typedef unsigned int   u32;
typedef __bf16 bf16x8 __attribute__((ext_vector_type(8)));
typedef float  f32x4  __attribute__((ext_vector_type(4)));
typedef unsigned short us4 __attribute__((ext_vector_type(4)));

#define EPSBN 1e-5f
#define PB_TOT 9344
// pblk: 0:stS1a[128] 128:stQ1a[128] 256:stS1b 320:stQ1b 384:stS2 448:stQ2
// 512:s1a[128] 640:t1a[128] 768:b1bF[64] 832:s1b 896:t1b 960:s2 1024:t2
// 1088:gmax[4096] 5184:gsum[4096] 9280:cnt[64]

__device__ __forceinline__ u32 f2bf1(float f){
    u32 u = __float_as_uint(f);
    return (u + 0x7FFFu + ((u >> 16) & 1u)) >> 16;
}
__device__ __forceinline__ float bf2f(u16 b){
    return __uint_as_float(((u32)b) << 16);
}
__device__ __forceinline__ u32 bsub2(u32 xj, u32 xi){
    float jl = __uint_as_float(xj << 16), jh = __uint_as_float(xj & 0xFFFF0000u);
    float il = __uint_as_float(xi << 16), ih = __uint_as_float(xi & 0xFFFF0000u);
    u32 lo = f2bf1(jl - il), hi = f2bf1(jh - ih);
    return lo | (hi << 16);
}
__device__ __forceinline__ void atomicMaxF(float* a, float v){
    if (v >= 0.f) atomicMax((int*)a, __float_as_int(v));
    else          atomicMin((u32*)a, __float_as_uint(v));
}
__device__ __forceinline__ int swz(int row, int k){
    return row*128 + (k ^ ((row & 7) << 3));
}
__device__ __forceinline__ int swz64(int row, int k){
    return row*64 + (k ^ ((row & 7) << 3));
}
__device__ __forceinline__ f32x4 mfma16(bf16x8 a, bf16x8 b, f32x4 c){
    return __builtin_amdgcn_mfma_f32_16x16x32_bf16(a, b, c, 0, 0, 0);
}

struct Pref { uint4 xi0, xi1, xj0, xj1; int dstS; };
__device__ __forceinline__ void load_tile(Pref& p, const u16* __restrict__ xb,
                                          const int2* __restrict__ ep,
                                          int t, int wave, int lane, int E){
    int eS = t*64 + wave*16 + (lane >> 2);
    if (eS < E){
        int2 sd = ep[eS];
        p.dstS = sd.y;
        int part = lane & 3;
        const uint4* pi = (const uint4*)(xb + (size_t)sd.y*64 + part*16);
        const uint4* pj = (const uint4*)(xb + (size_t)sd.x*64 + part*16);
        p.xi0 = pi[0]; p.xi1 = pi[1];
        p.xj0 = pj[0]; p.xj1 = pj[1];
    } else {
        uint4 z; z.x = z.y = z.z = z.w = 0u;
        p.xi0 = p.xi1 = p.xj0 = p.xj1 = z;
        p.dstS = -2;
    }
}
__device__ __forceinline__ void write_At(u16* At, const Pref& p, int wave, int lane){
    int part = lane & 3;
    int arow = wave*16 + (lane >> 2);
    *(uint4*)&At[swz(arow, part*16)]     = p.xi0;
    *(uint4*)&At[swz(arow, part*16+8)]   = p.xi1;
    uint4 e0, e1;
    e0.x = bsub2(p.xj0.x, p.xi0.x); e0.y = bsub2(p.xj0.y, p.xi0.y);
    e0.z = bsub2(p.xj0.z, p.xi0.z); e0.w = bsub2(p.xj0.w, p.xi0.w);
    e1.x = bsub2(p.xj1.x, p.xi1.x); e1.y = bsub2(p.xj1.y, p.xi1.y);
    e1.z = bsub2(p.xj1.z, p.xi1.z); e1.w = bsub2(p.xj1.w, p.xi1.w);
    *(uint4*)&At[swz(arow, 64+part*16)]   = e0;
    *(uint4*)&At[swz(arow, 64+part*16+8)] = e1;
}

__global__ void k_init(const float* __restrict__ x, u16* __restrict__ xb,
                       float* __restrict__ agg,
                       float* __restrict__ pblk, int* __restrict__ deg,
                       int NF, int N){
    int i = blockIdx.x*256 + threadIdx.x;
    if (i < NF){
        xb[i] = (u16)f2bf1(x[i]);
        agg[i] = -INFINITY;
    }
    if (i < N) deg[i] = 0;
    if (i < PB_TOT){
        pblk[i] = (i >= 1088 && i < 5184) ? -INFINITY : 0.f;
    }
}

__global__ void k_hist(const int* __restrict__ edst, int* __restrict__ deg, int E){
    int e = blockIdx.x*256 + threadIdx.x;
    if (e < E) atomicAdd(&deg[edst[e]], 1);
}

__global__ __launch_bounds__(1024) void k_scan(const int* __restrict__ deg,
                                               int* __restrict__ cursor, int N){
    __shared__ int buf[1024];
    __shared__ int carry;
    int tid = threadIdx.x;
    if (tid == 0) carry = 0;
    __syncthreads();
    for (int base = 0; base < N; base += 1024){
        int i = base + tid;
        int v = (i < N) ? deg[i] : 0;
        buf[tid] = v;
        __syncthreads();
        #pragma unroll
        for (int s = 1; s < 1024; s <<= 1){
            int a = (tid >= s) ? buf[tid - s] : 0;
            __syncthreads();
            buf[tid] += a;
            __syncthreads();
        }
        int inc = buf[tid] + carry;
        if (i < N) cursor[i] = inc - v;
        __syncthreads();
        if (tid == 1023) carry = inc;
        __syncthreads();
    }
}

__global__ void k_scatter(const int* __restrict__ esrc, const int* __restrict__ edst,
                          int* __restrict__ cursor, int2* __restrict__ ep, int E){
    int e = blockIdx.x*256 + threadIdx.x;
    if (e < E){
        int d = edst[e];
        int pos = atomicAdd(&cursor[d], 1);
        ep[pos] = make_int2(esrc[e], d);
    }
}

// pass1s: gather + GEMM-a + stats + spill h1a fragment-major (R6 verbatim).
__global__ __launch_bounds__(256) void k_pass1s(
    const u16* __restrict__ xb, const int2* __restrict__ ep,
    const float* __restrict__ W1a, const float* __restrict__ b1a,
    float* __restrict__ pblk, u16* __restrict__ h1a, int E, int nTiles)
{
    __shared__ u16 Wt[128*128];
    __shared__ u16 At[64*128];
    int tid = threadIdx.x;
    for (int i = tid; i < 128*128; i += 256){
        int k = i >> 7, n = i & 127;
        Wt[swz(n, k)] = (u16)f2bf1(W1a[i]);
    }
    __syncthreads();
    int lane = tid & 63, wave = tid >> 6;
    int lg = lane >> 4, lr = lane & 15;
    const float4* Bv = (const float4*)b1a;
    float runS[32], runQ[32];
    #pragma unroll
    for (int i = 0; i < 32; i++){ runS[i] = 0.f; runQ[i] = 0.f; }

    int t = blockIdx.x;
    Pref p;
    load_tile(p, xb, ep, t, wave, lane, E);
    for (; t < nTiles; t += gridDim.x){
        int tn = t + gridDim.x;
        Pref pn;
        if (tn < nTiles) load_tile(pn, xb, ep, tn, wave, lane, E);
        write_At(At, p, wave, lane);
        int row = wave*16 + lr;
        bf16x8 bfr[4];
        #pragma unroll
        for (int kt = 0; kt < 4; kt++)
            bfr[kt] = *(const bf16x8*)&At[swz(row, kt*32 + lg*8)];
        bool ev = (t*64 + wave*16 + lr) < E;
        #pragma unroll
        for (int mt = 0; mt < 8; mt++){
            f32x4 acc = {0.f,0.f,0.f,0.f};
            #pragma unroll
            for (int kt = 0; kt < 4; kt++){
                bf16x8 af = *(const bf16x8*)&Wt[swz(mt*16 + lr, kt*32 + lg*8)];
                acc = mfma16(af, bfr[kt], acc);
            }
            float4 bb = Bv[mt*4 + lg];
            const float* bbp = (const float*)&bb;
            us4 w;
            #pragma unroll
            for (int j = 0; j < 4; j++){
                float h = fmaxf(acc[j] + bbp[j], 0.f);
                if (ev){
                    runS[mt*4+j] += h;
                    runQ[mt*4+j] = fmaf(h, h, runQ[mt*4+j]);
                }
                w[j] = (u16)f2bf1(h);
            }
            *(us4*)&At[swz(row, mt*16 + lg*4)] = w;
        }
        #pragma unroll
        for (int kt = 0; kt < 4; kt++){
            uint4 v = *(const uint4*)&At[swz(row, kt*32 + lg*8)];
            *(uint4*)(h1a + ((((size_t)t*4 + wave)*4 + kt)*64 + lane)*8) = v;
        }
        if (tn < nTiles) p = pn;
    }
    #pragma unroll
    for (int i = 0; i < 32; i++){
        float s = runS[i], q = runQ[i];
        #pragma unroll
        for (int m = 1; m < 16; m <<= 1){ s += __shfl_xor(s, m); q += __shfl_xor(q, m); }
        if (lr == 0){
            int ch = (i >> 2)*16 + lg*4 + (i & 3);
            atomicAdd(&pblk[ch], s);
            atomicAdd(&pblk[128 + ch], q);
        }
    }
}

__global__ void k_fold1(const float* __restrict__ g1a, const float* __restrict__ bt1a,
                        const float* __restrict__ W1b, const float* __restrict__ b1b,
                        float* __restrict__ pblk, float fE)
{
    __shared__ float tS[128];
    int tid = threadIdx.x;
    if (tid < 128){
        float m = pblk[tid] * fE;
        float q = pblk[128 + tid] * fE;
        float v = fmaxf(q - m*m, 0.f);
        float s = g1a[tid] * rsqrtf(v + EPSBN);
        float t = bt1a[tid] - m*s;
        pblk[512 + tid] = s;
        pblk[640 + tid] = t;
        tS[tid] = t;
    }
    __syncthreads();
    if (tid < 64){
        float acc = b1b[tid];
        for (int k = 0; k < 128; k++) acc = fmaf(tS[k], W1b[k*64 + tid], acc);
        pblk[768 + tid] = acc;
    }
}

// pass2w: stream h1a spill, GEMM-b, stats1b, write h1b LINEARLY in-place over
// the consumed h1a region (wave-own 4KB; stores data-depend on the loads via
// MFMA, so RAW->WAR is safe). No ep, no atomics in loop, no shuffles.
// h1b layout: u16 offset t*8192 + wave*2048 + lr*64 + ch.
__global__ __launch_bounds__(256) void k_pass2w(
    u16* __restrict__ sp, const float* __restrict__ W1b,
    float* __restrict__ pblk, int E, int nTiles)
{
    __shared__ u16 Wt2[64*128];
    int tid = threadIdx.x;
    for (int i = tid; i < 64*128; i += 256){
        int k = i >> 6, n = i & 63;
        Wt2[swz(n, k)] = (u16)f2bf1(W1b[i] * pblk[512 + k]);
    }
    __syncthreads();
    int lane = tid & 63, wave = tid >> 6;
    int lg = lane >> 4, lr = lane & 15;
    float runS[16], runQ[16], b2r[16];
    #pragma unroll
    for (int i = 0; i < 16; i++){
        runS[i] = 0.f; runQ[i] = 0.f;
        b2r[i] = pblk[768 + (i >> 2)*16 + lg*4 + (i & 3)];
    }

    for (int t = blockIdx.x; t < nTiles; t += gridDim.x){
        bf16x8 br2[4];
        #pragma unroll
        for (int kt = 0; kt < 4; kt++)
            br2[kt] = *(const bf16x8*)(sp + ((((size_t)t*4 + wave)*4 + kt)*64 + lane)*8);
        bool ev = (t*64 + wave*16 + lr) < E;
        size_t hb = (size_t)t*8192 + wave*2048 + lr*64;
        #pragma unroll
        for (int mt = 0; mt < 4; mt++){
            f32x4 acc = {0.f,0.f,0.f,0.f};
            #pragma unroll
            for (int kt = 0; kt < 4; kt++){
                bf16x8 af = *(const bf16x8*)&Wt2[swz(mt*16 + lr, kt*32 + lg*8)];
                acc = mfma16(af, br2[kt], acc);
            }
            us4 w;
            #pragma unroll
            for (int j = 0; j < 4; j++){
                float h = fmaxf(acc[j] + b2r[mt*4 + j], 0.f);
                if (ev){
                    runS[mt*4 + j] += h;
                    runQ[mt*4 + j] = fmaf(h, h, runQ[mt*4 + j]);
                }
                w[j] = (u16)f2bf1(h);
            }
            *(us4*)(sp + hb + mt*16 + lg*4) = w;
        }
    }
    #pragma unroll
    for (int i = 0; i < 16; i++){
        float s = runS[i], q = runQ[i];
        #pragma unroll
        for (int m = 1; m < 16; m <<= 1){ s += __shfl_xor(s, m); q += __shfl_xor(q, m); }
        if (lr == 0){
            int ch = (i >> 2)*16 + lg*4 + (i & 3);
            atomicAdd(&pblk[256 + ch], s);
            atomicAdd(&pblk[320 + ch], q);
        }
    }
}

// pass2m: pull per-node max of h1b over CSR row range, apply BN1b, write x1b.
// One wave per node, lane = channel. No atomics.
__global__ __launch_bounds__(256) void k_pass2m(
    const u16* __restrict__ sp, const int* __restrict__ cursor,
    const int* __restrict__ deg, const float* __restrict__ pblk,
    u16* __restrict__ x1b, int N)
{
    int tid = threadIdx.x;
    int lane = tid & 63, wave = tid >> 6;
    float s1 = pblk[832 + lane], t1 = pblk[896 + lane];
    for (int n = blockIdx.x*4 + wave; n < N; n += gridDim.x*4){
        int d  = deg[n];
        int r0 = cursor[n] - d;
        float m = -INFINITY;
        for (int i = 0; i < d; ++i){
            int e = r0 + i;
            float h = bf2f(sp[(size_t)(e >> 6)*8192 + ((e >> 4) & 3)*2048 + (e & 15)*64 + lane]);
            m = fmaxf(m, h);
        }
        float v = (d > 0) ? fmaxf(fmaf(m, s1, t1), 0.f) : 0.f;
        x1b[(size_t)n*64 + lane] = (u16)f2bf1(v);
    }
}

__global__ void k_fold_st(const float* __restrict__ g, const float* __restrict__ bt,
                          float* __restrict__ pblk, float fE, int so, int qo, int os, int ot)
{
    int tid = threadIdx.x;
    if (tid < 64){
        float m = pblk[so + tid] * fE;
        float q = pblk[qo + tid] * fE;
        float v = fmaxf(q - m*m, 0.f);
        float s = g[tid] * rsqrtf(v + EPSBN);
        pblk[os + tid] = s;
        pblk[ot + tid] = bt[tid] - m*s;
    }
}

// Node GEMM -> bf16 PQ2 table (P=x1@(Wtop-Wbot)+b2 | Q=x1@Wbot).
__global__ __launch_bounds__(256) void k_ngemm128(
    const u16* __restrict__ xin, const float* __restrict__ Wsrc,
    const float* __restrict__ bias, u16* __restrict__ PQ, int N)
{
    __shared__ u16 Wt[128*64];
    __shared__ u16 At[64*64];
    int tid = threadIdx.x;
    for (int i = tid; i < 128*64; i += 256){
        int c = i >> 6, k = i & 63;
        float w = (c < 64) ? (Wsrc[k*64 + c] - Wsrc[(64+k)*64 + c])
                           : Wsrc[(64+k)*64 + (c - 64)];
        Wt[swz64(c, k)] = (u16)f2bf1(w);
    }
    int t = blockIdx.x;
    for (int i = tid; i < 512; i += 256){
        int row = i >> 3, ck = i & 7;
        int node = t*64 + row;
        uint4 v;
        if (node < N) v = *(const uint4*)(xin + (size_t)node*64 + ck*8);
        else { v.x = v.y = v.z = v.w = 0u; }
        *(uint4*)&At[swz64(row, ck*8)] = v;
    }
    __syncthreads();
    int lane = tid & 63, wave = tid >> 6;
    int lg = lane >> 4, lr = lane & 15;
    int row = wave*16 + lr;
    bf16x8 bfr[2];
    #pragma unroll
    for (int kt = 0; kt < 2; kt++)
        bfr[kt] = *(const bf16x8*)&At[swz64(row, kt*32 + lg*8)];
    int node = t*64 + wave*16 + lr;
    #pragma unroll
    for (int mt = 0; mt < 8; mt++){
        f32x4 acc = {0.f,0.f,0.f,0.f};
        #pragma unroll
        for (int kt = 0; kt < 2; kt++){
            bf16x8 af = *(const bf16x8*)&Wt[swz64(mt*16 + lr, kt*32 + lg*8)];
            acc = mfma16(af, bfr[kt], acc);
        }
        int ch = mt*16 + lg*4;
        float r[4] = {acc[0], acc[1], acc[2], acc[3]};
        if (ch < 64){
            float4 bb = *(const float4*)(bias + ch);
            r[0] += bb.x; r[1] += bb.y; r[2] += bb.z; r[3] += bb.w;
        }
        if (node < N){
            us4 w4;
            #pragma unroll
            for (int j = 0; j < 4; j++) w4[j] = (u16)f2bf1(r[j]);
            *(us4*)(PQ + (size_t)node*128 + ch) = w4;
        }
    }
}

// pass3p: PULL-based conv2 (R10 verbatim).
__global__ __launch_bounds__(256) void k_pass3p(
    const u16* __restrict__ PQ2, const int2* __restrict__ ep,
    const int* __restrict__ cursor, const int* __restrict__ deg,
    float* __restrict__ pblk, float* __restrict__ agg, int N)
{
    int tid = threadIdx.x;
    int lane = tid & 63, wave = tid >> 6;
    float runS = 0.f, runQ = 0.f;
    const int* epi = (const int*)ep;

    for (int n = blockIdx.x*4 + wave; n < N; n += gridDim.x*4){
        int d  = deg[n];
        int r0 = cursor[n] - d;
        float p = bf2f(PQ2[(size_t)n*128 + lane]);
        float mq = -INFINITY;
        int src = (d > 0) ? epi[2*r0] : 0;
        for (int i = 0; i < d; ++i){
            int srcn = (i + 1 < d) ? epi[2*(r0 + i + 1)] : 0;
            float q = bf2f(PQ2[(size_t)src*128 + 64 + lane]);
            mq = fmaxf(mq, q);
            float h = fmaxf(p + q, 0.f);
            runS += h;
            runQ = fmaf(h, h, runQ);
            src = srcn;
        }
        if (d > 0) agg[(size_t)n*64 + lane] = mq;
    }
    __shared__ float bS[256], bQ[256];
    bS[tid] = runS; bQ[tid] = runQ;
    __syncthreads();
    if (wave == 0){
        float s = bS[lane] + bS[64 + lane] + bS[128 + lane] + bS[192 + lane];
        float q = bQ[lane] + bQ[64 + lane] + bQ[128 + lane] + bQ[192 + lane];
        atomicAdd(&pblk[384 + lane], s);
        atomicAdd(&pblk[448 + lane], q);
    }
}

#define FUSE_NODES 128
__global__ __launch_bounds__(256) void k_fuse(const float* __restrict__ agg,
                                              const u16* __restrict__ x1b,
                                              const u16* __restrict__ PQ2,
                                              const int* __restrict__ batch,
                                              float* __restrict__ pblk, int N)
{
    int c = threadIdx.x & 63, r = threadIdx.x >> 6;
    int n0 = blockIdx.x*FUSE_NODES + r*(FUSE_NODES/4);
    if (n0 >= N) return;
    int n1 = n0 + FUSE_NODES/4; if (n1 > N) n1 = N;
    float s2c = pblk[960 + c], t2c = pblk[1024 + c];
    float gm = -INFINITY, gs = 0.f;
    int cur = batch[n0], cnt0 = 0;
    for (int n = n0; n < n1; ++n){
        int g = batch[n];
        if (g != cur){
            atomicMaxF(&pblk[1088 + cur*64 + c], gm);
            atomicAdd(&pblk[5184 + cur*64 + c], gs);
            if (c == 0) atomicAdd(&pblk[9280 + cur], (float)cnt0);
            gm = -INFINITY; gs = 0.f; cnt0 = 0; cur = g;
        }
        float a = agg[(size_t)n*64 + c];   // maxQ2 (or -inf if no in-edges)
        float v;
        if (a > -INFINITY){
            float p = bf2f(PQ2[(size_t)n*128 + c]);
            float pre = fmaxf(p + a, 0.f);
            v = fmaxf(fmaf(pre, s2c, t2c), 0.f);
        } else v = 0.f;
        float f = bf2f(x1b[(size_t)n*64 + c]) + v;
        gm = fmaxf(gm, f); gs += f; cnt0++;
    }
    atomicMaxF(&pblk[1088 + cur*64 + c], gm);
    atomicAdd(&pblk[5184 + cur*64 + c], gs);
    if (c == 0) atomicAdd(&pblk[9280 + cur], (float)cnt0);
}

__global__ void k_out(const float* __restrict__ pblk, float* __restrict__ out)
{
    int i = blockIdx.x*256 + threadIdx.x;
    if (i >= 64*128) return;
    int g = i >> 7, c = i & 127;
    float r;
    if (c < 64){
        float m = pblk[1088 + g*64 + c];
        r = (m > -INFINITY) ? m : 0.f;
    } else {
        float s = pblk[5184 + g*64 + (c - 64)];
        float n = pblk[9280 + g];
        r = s / fmaxf(n, 1.f);
    }
    out[i] = r;
}

extern "C" void kernel_launch(void* const* d_in, const int* in_sizes, int n_in,
                              void* d_out, int out_size, void* d_ws, size_t ws_size,
                              hipStream_t stream)
{
    const float* x    = (const float*)d_in[0];
    const int*   ei   = (const int*)  d_in[1];
    const int*   batch= (const int*)  d_in[2];
    const float* W1a  = (const float*)d_in[3];
    const float* b1a  = (const float*)d_in[4];
    const float* g1a  = (const float*)d_in[5];
    const float* bt1a = (const float*)d_in[6];
    const float* W1b  = (const float*)d_in[7];
    const float* b1b  = (const float*)d_in[8];
    const float* g1b  = (const float*)d_in[9];
    const float* bt1b = (const float*)d_in[10];
    const float* W2   = (const float*)d_in[11];
    const float* b2   = (const float*)d_in[12];
    const float* g2   = (const float*)d_in[13];
    const float* bt2  = (const float*)d_in[14];

    int N  = in_sizes[0] / 64;
    int E  = in_sizes[1] / 2;
    int NF = N * 64;
    int nTiles = (E + 63) / 64;

    char* ws = (char*)d_ws;
    size_t off = 0;
    auto alloc = [&](size_t bytes){ size_t o = off; off += (bytes + 255) & ~(size_t)255; return o; };
    u16*   xb    = (u16*)  (ws + alloc((size_t)NF*2));
    u16*   x1b   = (u16*)  (ws + alloc((size_t)NF*2));
    float* agg   = (float*)(ws + alloc((size_t)NF*4));
    float* pblk  = (float*)(ws + alloc((size_t)PB_TOT*4));
    int*   deg   = (int*)  (ws + alloc((size_t)N*4));
    int*   cursor= (int*)  (ws + alloc((size_t)N*4));
    int2*  ep    = (int2*) (ws + alloc((size_t)E*8));
    u16*   sp    = (u16*)  (ws + alloc((size_t)nTiles*64*128*2));  // h1a spill / h1b
    u16*   PQ2   = sp;   // aliases spill region (dead after k_pass2m)
    (void)ws_size;       // layout == R6/R9/R10-proven 237.7MB

    const int* esrc = ei;
    const int* edst = ei + E;
    int gPass  = nTiles < 2048 ? nTiles : 2048;
    int gElem  = (NF + 255) / 256;
    int gEdge  = (E + 255) / 256;
    int gNode  = (N + 63) / 64;
    int gPull  = ((N + 3) / 4) < 2048 ? ((N + 3) / 4) : 2048;
    float fE   = 1.f / (float)E;

    k_init    <<<gElem, 256, 0, stream>>>(x, xb, agg, pblk, deg, NF, N);
    k_hist    <<<gEdge, 256, 0, stream>>>(edst, deg, E);
    k_scan    <<<1, 1024, 0, stream>>>(deg, cursor, N);
    k_scatter <<<gEdge, 256, 0, stream>>>(esrc, edst, cursor, ep, E);
    k_pass1s  <<<gPass, 256, 0, stream>>>(xb, ep, W1a, b1a, pblk, sp, E, nTiles);
    k_fold1   <<<1, 128, 0, stream>>>(g1a, bt1a, W1b, b1b, pblk, fE);
    k_pass2w  <<<gPass, 256, 0, stream>>>(sp, W1b, pblk, E, nTiles);
    k_fold_st <<<1, 64, 0, stream>>>(g1b, bt1b, pblk, fE, 256, 320, 832, 896);
    k_pass2m  <<<gPull, 256, 0, stream>>>(sp, cursor, deg, pblk, x1b, N);
    k_ngemm128<<<gNode, 256, 0, stream>>>(x1b, W2, b2, PQ2, N);
    k_pass3p  <<<gPull, 256, 0, stream>>>(PQ2, ep, cursor, deg, pblk, agg, N);
    k_fold_st <<<1, 64, 0, stream>>>(g2, bt2, pblk, fE, 384, 448, 960, 1024);
    k_fuse    <<<(N + FUSE_NODES - 1)/FUSE_NODES, 256, 0, stream>>>(agg, x1b, PQ2, batch, pblk, N);
    k_out     <<<32, 256, 0, stream>>>(pblk, (float*)d_out);
}

// Round 12
// 1411.044 us; speedup vs baseline: 1.5026x; 1.5026x over previous
//
#include <hip/hip_runtime.h>
#include <math.h>

// GraphNet: 2x EdgeConv (E=800k, F=H=64) + BN folded/commuted + pooling.
// R12: conv1 fully PULL-based (the push-tile shape costs ~890us regardless of
// content; pull-CSR kernels are fast — R10/R11 evidence).
//  ngemm256 -> PQ1 bf16 (h1a_edge = relu(P1[dst]+Q1[src]), R8-proven)
//  pass1p: pull stats1a (1 u32 load/edge/lane, no spill)
//  pass2p: pull GEMM-b: folded W1b column in 64 packed-bf16 VGPRs;
//          per edge 64x {readlane-broadcast h-pair + 2 FMA}; stats1b +
//          per-node max h1b (pre-BN, monotone) via plain store.
// conv2 unchanged (ngemm128 + pass3p pull, R10-proven). No spill: ws ~71MB.

typedef unsigned short u16;
typedef unsigned int   u32;
typedef __bf16 bf16x8 __attribute__((ext_vector_type(8)));
typedef float  f32x4  __attribute__((ext_vector_type(4)));
typedef unsigned short us4 __attribute__((ext_vector_type(4)));

#define EPSBN 1e-5f
#define PB_TOT 9344
// pblk: 0:stS1a[128] 128:stQ1a[128] 256:stS1b 320:stQ1b 384:stS2 448:stQ2
// 512:s1a[128] 640:t1a[128] 768:b1bF[64] 832:s1b 896:t1b 960:s2 1024:t2
// 1088:gmax[4096] 5184:gsum[4096] 9280:cnt[64]

__device__ __forceinline__ u32 f2bf1(float f){
    u32 u = __float_as_uint(f);
    return (u + 0x7FFFu + ((u >> 16) & 1u)) >> 16;
}
__device__ __forceinline__ float bf2f(u16 b){
    return __uint_as_float(((u32)b) << 16);
}
__device__ __forceinline__ void atomicMaxF(float* a, float v){
    if (v >= 0.f) atomicMax((int*)a, __float_as_int(v));
    else          atomicMin((u32*)a, __float_as_uint(v));
}
__device__ __forceinline__ int swz64(int row, int k){
    return row*64 + (k ^ ((row & 7) << 3));
}
__device__ __forceinline__ f32x4 mfma16(bf16x8 a, bf16x8 b, f32x4 c){
    return __builtin_amdgcn_mfma_f32_16x16x32_bf16(a, b, c, 0, 0, 0);
}

__global__ void k_init(const float* __restrict__ x, u16* __restrict__ xb,
                       float* __restrict__ agg,
                       float* __restrict__ pblk, int* __restrict__ deg,
                       int NF, int N){
    int i = blockIdx.x*256 + threadIdx.x;
    if (i < NF){
        xb[i] = (u16)f2bf1(x[i]);
        agg[i] = -INFINITY;
    }
    if (i < N) deg[i] = 0;
    if (i < PB_TOT){
        pblk[i] = (i >= 1088 && i < 5184) ? -INFINITY : 0.f;
    }
}

__global__ void k_hist(const int* __restrict__ edst, int* __restrict__ deg, int E){
    int e = blockIdx.x*256 + threadIdx.x;
    if (e < E) atomicAdd(&deg[edst[e]], 1);
}

__global__ __launch_bounds__(1024) void k_scan(const int* __restrict__ deg,
                                               int* __restrict__ cursor, int N){
    __shared__ int buf[1024];
    __shared__ int carry;
    int tid = threadIdx.x;
    if (tid == 0) carry = 0;
    __syncthreads();
    for (int base = 0; base < N; base += 1024){
        int i = base + tid;
        int v = (i < N) ? deg[i] : 0;
        buf[tid] = v;
        __syncthreads();
        #pragma unroll
        for (int s = 1; s < 1024; s <<= 1){
            int a = (tid >= s) ? buf[tid - s] : 0;
            __syncthreads();
            buf[tid] += a;
            __syncthreads();
        }
        int inc = buf[tid] + carry;
        if (i < N) cursor[i] = inc - v;
        __syncthreads();
        if (tid == 1023) carry = inc;
        __syncthreads();
    }
}

__global__ void k_scatter(const int* __restrict__ esrc, const int* __restrict__ edst,
                          int* __restrict__ cursor, int2* __restrict__ ep, int E){
    int e = blockIdx.x*256 + threadIdx.x;
    if (e < E){
        int d = edst[e];
        int pos = atomicAdd(&cursor[d], 1);
        ep[pos] = make_int2(esrc[e], d);
    }
}

// Node GEMM -> bf16 PQ table (R8-proven). PQ[n][c]: c<WC -> P=x@(Wtop-Wbot)
// +bias, c>=WC -> Q=x@Wbot.
template<int COUT>
__global__ __launch_bounds__(256) void k_ngemm(
    const u16* __restrict__ xin, const float* __restrict__ Wsrc,
    const float* __restrict__ bias, u16* __restrict__ PQ, int N)
{
    const int WC = COUT/2;
    __shared__ u16 Wt[COUT*64];
    __shared__ u16 At[64*64];
    int tid = threadIdx.x;
    for (int i = tid; i < COUT*64; i += 256){
        int c = i >> 6, k = i & 63;
        float w = (c < WC) ? (Wsrc[k*WC + c] - Wsrc[(64+k)*WC + c])
                           : Wsrc[(64+k)*WC + (c - WC)];
        Wt[swz64(c, k)] = (u16)f2bf1(w);
    }
    int t = blockIdx.x;
    for (int i = tid; i < 512; i += 256){
        int row = i >> 3, ck = i & 7;
        int node = t*64 + row;
        uint4 v;
        if (node < N) v = *(const uint4*)(xin + (size_t)node*64 + ck*8);
        else { v.x = v.y = v.z = v.w = 0u; }
        *(uint4*)&At[swz64(row, ck*8)] = v;
    }
    __syncthreads();
    int lane = tid & 63, wave = tid >> 6;
    int lg = lane >> 4, lr = lane & 15;
    int row = wave*16 + lr;
    bf16x8 bfr[2];
    #pragma unroll
    for (int kt = 0; kt < 2; kt++)
        bfr[kt] = *(const bf16x8*)&At[swz64(row, kt*32 + lg*8)];
    int node = t*64 + wave*16 + lr;
    #pragma unroll
    for (int mt = 0; mt < COUT/16; mt++){
        f32x4 acc = {0.f,0.f,0.f,0.f};
        #pragma unroll
        for (int kt = 0; kt < 2; kt++){
            bf16x8 af = *(const bf16x8*)&Wt[swz64(mt*16 + lr, kt*32 + lg*8)];
            acc = mfma16(af, bfr[kt], acc);
        }
        int ch = mt*16 + lg*4;
        float r[4] = {acc[0], acc[1], acc[2], acc[3]};
        if (ch < WC){
            float4 bb = *(const float4*)(bias + ch);
            r[0] += bb.x; r[1] += bb.y; r[2] += bb.z; r[3] += bb.w;
        }
        if (node < N){
            us4 w4;
            #pragma unroll
            for (int j = 0; j < 4; j++) w4[j] = (u16)f2bf1(r[j]);
            *(us4*)(PQ + (size_t)node*COUT + ch) = w4;
        }
    }
}

// pass1p: pull BN1a stats. lane handles ch {2*lane, 2*lane+1} of 128.
__global__ __launch_bounds__(256) void k_pass1p(
    const u16* __restrict__ PQ1, const int2* __restrict__ ep,
    const int* __restrict__ cursor, const int* __restrict__ deg,
    float* __restrict__ pblk, int N)
{
    int tid = threadIdx.x;
    int lane = tid & 63, wave = tid >> 6;
    float s0 = 0.f, s1 = 0.f, q0 = 0.f, q1 = 0.f;
    const int* epi = (const int*)ep;

    for (int n = blockIdx.x*4 + wave; n < N; n += gridDim.x*4){
        int d  = deg[n];
        int r0 = cursor[n] - d;
        u32 pp = *(const u32*)(PQ1 + (size_t)n*256 + 2*lane);
        float p0 = bf2f((u16)(pp & 0xFFFFu)), p1 = bf2f((u16)(pp >> 16));
        int src = (d > 0) ? epi[2*r0] : 0;
        for (int i = 0; i < d; ++i){
            int srcn = (i + 1 < d) ? epi[2*(r0 + i + 1)] : 0;
            u32 qq = *(const u32*)(PQ1 + (size_t)src*256 + 128 + 2*lane);
            float h0 = fmaxf(p0 + bf2f((u16)(qq & 0xFFFFu)), 0.f);
            float h1 = fmaxf(p1 + bf2f((u16)(qq >> 16)), 0.f);
            s0 += h0; q0 = fmaf(h0, h0, q0);
            s1 += h1; q1 = fmaf(h1, h1, q1);
            src = srcn;
        }
    }
    __shared__ float bS0[256], bS1[256], bQ0[256], bQ1[256];
    bS0[tid] = s0; bS1[tid] = s1; bQ0[tid] = q0; bQ1[tid] = q1;
    __syncthreads();
    if (wave == 0){
        float a0 = bS0[lane] + bS0[64+lane] + bS0[128+lane] + bS0[192+lane];
        float a1 = bS1[lane] + bS1[64+lane] + bS1[128+lane] + bS1[192+lane];
        float c0 = bQ0[lane] + bQ0[64+lane] + bQ0[128+lane] + bQ0[192+lane];
        float c1 = bQ1[lane] + bQ1[64+lane] + bQ1[128+lane] + bQ1[192+lane];
        atomicAdd(&pblk[2*lane],       a0);
        atomicAdd(&pblk[2*lane + 1],   a1);
        atomicAdd(&pblk[128 + 2*lane],     c0);
        atomicAdd(&pblk[128 + 2*lane + 1], c1);
    }
}

__global__ void k_fold1(const float* __restrict__ g1a, const float* __restrict__ bt1a,
                        const float* __restrict__ W1b, const float* __restrict__ b1b,
                        float* __restrict__ pblk, float fE)
{
    __shared__ float tS[128];
    int tid = threadIdx.x;
    if (tid < 128){
        float m = pblk[tid] * fE;
        float q = pblk[128 + tid] * fE;
        float v = fmaxf(q - m*m, 0.f);
        float s = g1a[tid] * rsqrtf(v + EPSBN);
        float t = bt1a[tid] - m*s;
        pblk[512 + tid] = s;
        pblk[640 + tid] = t;
        tS[tid] = t;
    }
    __syncthreads();
    if (tid < 64){
        float acc = b1b[tid];
        for (int k = 0; k < 128; k++) acc = fmaf(tS[k], W1b[k*64 + tid], acc);
        pblk[768 + tid] = acc;
    }
}

// pass2p: pull GEMM-b. lane = output channel c. Folded column
// w[kk] = pack_bf16(s1a[2kk]*W1b[2kk][c], s1a[2kk+1]*W1b[2kk+1][c]) in VGPRs.
// Per edge: h-pair (packed bf16) -> 64x {__shfl broadcast (literal lane ->
// v_readlane) + 2 FMA}. stats1b + per-node max h1b (plain store into agg).
__global__ __launch_bounds__(256) void k_pass2p(
    const u16* __restrict__ PQ1, const int2* __restrict__ ep,
    const int* __restrict__ cursor, const int* __restrict__ deg,
    const float* __restrict__ W1b,
    float* __restrict__ pblk, float* __restrict__ agg, int N)
{
    int tid = threadIdx.x;
    int lane = tid & 63, wave = tid >> 6;
    u32 w[64];
    #pragma unroll
    for (int kk = 0; kk < 64; kk++){
        float w0 = pblk[512 + 2*kk]     * W1b[(2*kk)*64 + lane];
        float w1 = pblk[512 + 2*kk + 1] * W1b[(2*kk + 1)*64 + lane];
        w[kk] = f2bf1(w0) | (f2bf1(w1) << 16);
    }
    float bc = pblk[768 + lane];
    float runS = 0.f, runQ = 0.f;
    const int* epi = (const int*)ep;

    for (int n = blockIdx.x*4 + wave; n < N; n += gridDim.x*4){
        int d  = deg[n];
        int r0 = cursor[n] - d;
        u32 pp = *(const u32*)(PQ1 + (size_t)n*256 + 2*lane);
        float p0 = bf2f((u16)(pp & 0xFFFFu)), p1 = bf2f((u16)(pp >> 16));
        float mh = -INFINITY;
        int src = (d > 0) ? epi[2*r0] : 0;
        for (int i = 0; i < d; ++i){
            int srcn = (i + 1 < d) ? epi[2*(r0 + i + 1)] : 0;
            u32 qq = *(const u32*)(PQ1 + (size_t)src*256 + 128 + 2*lane);
            float h0 = fmaxf(p0 + bf2f((u16)(qq & 0xFFFFu)), 0.f);
            float h1 = fmaxf(p1 + bf2f((u16)(qq >> 16)), 0.f);
            u32 hp = f2bf1(h0) | (f2bf1(h1) << 16);
            float acc = 0.f;
            #pragma unroll
            for (int kk = 0; kk < 64; kk++){
                u32 hb = (u32)__shfl((int)hp, kk, 64);
                acc = fmaf(bf2f((u16)(hb & 0xFFFFu)), bf2f((u16)(w[kk] & 0xFFFFu)), acc);
                acc = fmaf(bf2f((u16)(hb >> 16)),     bf2f((u16)(w[kk] >> 16)),     acc);
            }
            float hb1 = fmaxf(acc + bc, 0.f);
            runS += hb1;
            runQ = fmaf(hb1, hb1, runQ);
            mh = fmaxf(mh, hb1);
            src = srcn;
        }
        if (d > 0) agg[(size_t)n*64 + lane] = mh;
    }
    __shared__ float bS[256], bQ[256];
    bS[tid] = runS; bQ[tid] = runQ;
    __syncthreads();
    if (wave == 0){
        float s = bS[lane] + bS[64+lane] + bS[128+lane] + bS[192+lane];
        float q = bQ[lane] + bQ[64+lane] + bQ[128+lane] + bQ[192+lane];
        atomicAdd(&pblk[256 + lane], s);
        atomicAdd(&pblk[320 + lane], q);
    }
}

__global__ void k_fold_st(const float* __restrict__ g, const float* __restrict__ bt,
                          float* __restrict__ pblk, float fE, int so, int qo, int os, int ot)
{
    int tid = threadIdx.x;
    if (tid < 64){
        float m = pblk[so + tid] * fE;
        float q = pblk[qo + tid] * fE;
        float v = fmaxf(q - m*m, 0.f);
        float s = g[tid] * rsqrtf(v + EPSBN);
        pblk[os + tid] = s;
        pblk[ot + tid] = bt[tid] - m*s;
    }
}

// x1 = relu(bn1b(agg) or 0) -> x1b; reset agg to -inf for pass3p reuse.
__global__ void k_x1(float* __restrict__ agg, const float* __restrict__ pblk,
                     u16* __restrict__ x1b, int NF)
{
    int i = blockIdx.x*256 + threadIdx.x;
    if (i >= NF) return;
    int c = i & 63;
    float a = agg[i];
    float v = (a > -INFINITY) ? fmaf(a, pblk[832 + c], pblk[896 + c]) : 0.f;
    v = fmaxf(v, 0.f);
    x1b[i] = (u16)f2bf1(v);
    agg[i] = -INFINITY;
}

// pass3p: PULL-based conv2 (R10 verbatim).
__global__ __launch_bounds__(256) void k_pass3p(
    const u16* __restrict__ PQ2, const int2* __restrict__ ep,
    const int* __restrict__ cursor, const int* __restrict__ deg,
    float* __restrict__ pblk, float* __restrict__ agg, int N)
{
    int tid = threadIdx.x;
    int lane = tid & 63, wave = tid >> 6;
    float runS = 0.f, runQ = 0.f;
    const int* epi = (const int*)ep;

    for (int n = blockIdx.x*4 + wave; n < N; n += gridDim.x*4){
        int d  = deg[n];
        int r0 = cursor[n] - d;
        float p = bf2f(PQ2[(size_t)n*128 + lane]);
        float mq = -INFINITY;
        int src = (d > 0) ? epi[2*r0] : 0;
        for (int i = 0; i < d; ++i){
            int srcn = (i + 1 < d) ? epi[2*(r0 + i + 1)] : 0;
            float q = bf2f(PQ2[(size_t)src*128 + 64 + lane]);
            mq = fmaxf(mq, q);
            float h = fmaxf(p + q, 0.f);
            runS += h;
            runQ = fmaf(h, h, runQ);
            src = srcn;
        }
        if (d > 0) agg[(size_t)n*64 + lane] = mq;
    }
    __shared__ float bS[256], bQ[256];
    bS[tid] = runS; bQ[tid] = runQ;
    __syncthreads();
    if (wave == 0){
        float s = bS[lane] + bS[64 + lane] + bS[128 + lane] + bS[192 + lane];
        float q = bQ[lane] + bQ[64 + lane] + bQ[128 + lane] + bQ[192 + lane];
        atomicAdd(&pblk[384 + lane], s);
        atomicAdd(&pblk[448 + lane], q);
    }
}

#define FUSE_NODES 128
__global__ __launch_bounds__(256) void k_fuse(const float* __restrict__ agg,
                                              const u16* __restrict__ x1b,
                                              const u16* __restrict__ PQ2,
                                              const int* __restrict__ batch,
                                              float* __restrict__ pblk, int N)
{
    int c = threadIdx.x & 63, r = threadIdx.x >> 6;
    int n0 = blockIdx.x*FUSE_NODES + r*(FUSE_NODES/4);
    if (n0 >= N) return;
    int n1 = n0 + FUSE_NODES/4; if (n1 > N) n1 = N;
    float s2c = pblk[960 + c], t2c = pblk[1024 + c];
    float gm = -INFINITY, gs = 0.f;
    int cur = batch[n0], cnt0 = 0;
    for (int n = n0; n < n1; ++n){
        int g = batch[n];
        if (g != cur){
            atomicMaxF(&pblk[1088 + cur*64 + c], gm);
            atomicAdd(&pblk[5184 + cur*64 + c], gs);
            if (c == 0) atomicAdd(&pblk[9280 + cur], (float)cnt0);
            gm = -INFINITY; gs = 0.f; cnt0 = 0; cur = g;
        }
        float a = agg[(size_t)n*64 + c];   // maxQ2 (or -inf if no in-edges)
        float v;
        if (a > -INFINITY){
            float p = bf2f(PQ2[(size_t)n*128 + c]);
            float pre = fmaxf(p + a, 0.f);
            v = fmaxf(fmaf(pre, s2c, t2c), 0.f);
        } else v = 0.f;
        float f = bf2f(x1b[(size_t)n*64 + c]) + v;
        gm = fmaxf(gm, f); gs += f; cnt0++;
    }
    atomicMaxF(&pblk[1088 + cur*64 + c], gm);
    atomicAdd(&pblk[5184 + cur*64 + c], gs);
    if (c == 0) atomicAdd(&pblk[9280 + cur], (float)cnt0);
}

__global__ void k_out(const float* __restrict__ pblk, float* __restrict__ out)
{
    int i = blockIdx.x*256 + threadIdx.x;
    if (i >= 64*128) return;
    int g = i >> 7, c = i & 127;
    float r;
    if (c < 64){
        float m = pblk[1088 + g*64 + c];
        r = (m > -INFINITY) ? m : 0.f;
    } else {
        float s = pblk[5184 + g*64 + (c - 64)];
        float n = pblk[9280 + g];
        r = s / fmaxf(n, 1.f);
    }
    out[i] = r;
}

extern "C" void kernel_launch(void* const* d_in, const int* in_sizes, int n_in,
                              void* d_out, int out_size, void* d_ws, size_t ws_size,
                              hipStream_t stream)
{
    const float* x    = (const float*)d_in[0];
    const int*   ei   = (const int*)  d_in[1];
    const int*   batch= (const int*)  d_in[2];
    const float* W1a  = (const float*)d_in[3];
    const float* b1a  = (const float*)d_in[4];
    const float* g1a  = (const float*)d_in[5];
    const float* bt1a = (const float*)d_in[6];
    const float* W1b  = (const float*)d_in[7];
    const float* b1b  = (const float*)d_in[8];
    const float* g1b  = (const float*)d_in[9];
    const float* bt1b = (const float*)d_in[10];
    const float* W2   = (const float*)d_in[11];
    const float* b2   = (const float*)d_in[12];
    const float* g2   = (const float*)d_in[13];
    const float* bt2  = (const float*)d_in[14];

    int N  = in_sizes[0] / 64;
    int E  = in_sizes[1] / 2;
    int NF = N * 64;

    char* ws = (char*)d_ws;
    size_t off = 0;
    auto alloc = [&](size_t bytes){ size_t o = off; off += (bytes + 255) & ~(size_t)255; return o; };
    u16*   xb    = (u16*)  (ws + alloc((size_t)NF*2));
    u16*   x1b   = (u16*)  (ws + alloc((size_t)NF*2));
    float* agg   = (float*)(ws + alloc((size_t)NF*4));
    float* pblk  = (float*)(ws + alloc((size_t)PB_TOT*4));
    int*   deg   = (int*)  (ws + alloc((size_t)N*4));
    int*   cursor= (int*)  (ws + alloc((size_t)N*4));
    int2*  ep    = (int2*) (ws + alloc((size_t)E*8));
    u16*   PQ1   = (u16*)  (ws + alloc((size_t)N*256*2));
    u16*   PQ2   = (u16*)  (ws + alloc((size_t)N*128*2));
    (void)ws_size;   // ~71MB << proven 237.7MB budget

    const int* esrc = ei;
    const int* edst = ei + E;
    int gElem  = (NF + 255) / 256;
    int gEdge  = (E + 255) / 256;
    int gNode  = (N + 63) / 64;
    int gPull  = ((N + 3) / 4) < 2048 ? ((N + 3) / 4) : 2048;
    float fE   = 1.f / (float)E;

    k_init      <<<gElem, 256, 0, stream>>>(x, xb, agg, pblk, deg, NF, N);
    k_hist      <<<gEdge, 256, 0, stream>>>(edst, deg, E);
    k_scan      <<<1, 1024, 0, stream>>>(deg, cursor, N);
    k_scatter   <<<gEdge, 256, 0, stream>>>(esrc, edst, cursor, ep, E);
    k_ngemm<256><<<gNode, 256, 0, stream>>>(xb, W1a, b1a, PQ1, N);
    k_pass1p    <<<gPull, 256, 0, stream>>>(PQ1, ep, cursor, deg, pblk, N);
    k_fold1     <<<1, 128, 0, stream>>>(g1a, bt1a, W1b, b1b, pblk, fE);
    k_pass2p    <<<gPull, 256, 0, stream>>>(PQ1, ep, cursor, deg, W1b, pblk, agg, N);
    k_fold_st   <<<1, 64, 0, stream>>>(g1b, bt1b, pblk, fE, 256, 320, 832, 896);
    k_x1        <<<gElem, 256, 0, stream>>>(agg, pblk, x1b, NF);
    k_ngemm<128><<<gNode, 256, 0, stream>>>(x1b, W2, b2, PQ2, N);
    k_pass3p    <<<gPull, 256, 0, stream>>>(PQ2, ep, cursor, deg, pblk, agg, N);
    k_fold_st   <<<1, 64, 0, stream>>>(g2, bt2, pblk, fE, 384, 448, 960, 1024);
    k_fuse      <<<(N + FUSE_NODES - 1)/FUSE_NODES, 256, 0, stream>>>(agg, x1b, PQ2, batch, pblk, N);
    k_out       <<<32, 256, 0, stream>>>(pblk, (float*)d_out);
}

// Round 13
// 1274.054 us; speedup vs baseline: 1.6641x; 1.1075x over previous
//
#include <hip/hip_runtime.h>
#include <math.h>

// GraphNet: 2x EdgeConv (E=800k, F=H=64) + BN folded/commuted + pooling.
// R13: pass2p's in-register GEMM-b vectorized. PQ1 table switched bf16->f16
// (more mantissa at these magnitudes); h1a pair via packed f16 add+relu;
// inner loop = 64x { readlane broadcast + v_dot2_f32_f16 } (~130 instr/edge
// vs R12's ~450). Fallback to manual FMA if fdot2 builtin missing.
// Everything else R12-verbatim (pull-CSR conv1+conv2, proven 1411us).

typedef unsigned short u16;
typedef unsigned int   u32;
typedef __bf16 bf16x8 __attribute__((ext_vector_type(8)));
typedef float  f32x4  __attribute__((ext_vector_type(4)));
typedef unsigned short us4 __attribute__((ext_vector_type(4)));
typedef _Float16 f16;
typedef f16 f16x2 __attribute__((ext_vector_type(2)));

#define EPSBN 1e-5f
#define PB_TOT 9344
// pblk: 0:stS1a[128] 128:stQ1a[128] 256:stS1b 320:stQ1b 384:stS2 448:stQ2
// 512:s1a[128] 640:t1a[128] 768:b1bF[64] 832:s1b 896:t1b 960:s2 1024:t2
// 1088:gmax[4096] 5184:gsum[4096] 9280:cnt[64]

#if __has_builtin(__builtin_amdgcn_fdot2)
#define HAS_FDOT2 1
#else
#define HAS_FDOT2 0
#endif

__device__ __forceinline__ u32 f2bf1(float f){
    u32 u = __float_as_uint(f);
    return (u + 0x7FFFu + ((u >> 16) & 1u)) >> 16;
}
__device__ __forceinline__ float bf2f(u16 b){
    return __uint_as_float(((u32)b) << 16);
}
__device__ __forceinline__ void atomicMaxF(float* a, float v){
    if (v >= 0.f) atomicMax((int*)a, __float_as_int(v));
    else          atomicMin((u32*)a, __float_as_uint(v));
}
__device__ __forceinline__ int swz64(int row, int k){
    return row*64 + (k ^ ((row & 7) << 3));
}
__device__ __forceinline__ f32x4 mfma16(bf16x8 a, bf16x8 b, f32x4 c){
    return __builtin_amdgcn_mfma_f32_16x16x32_bf16(a, b, c, 0, 0, 0);
}

__global__ void k_init(const float* __restrict__ x, u16* __restrict__ xb,
                       float* __restrict__ agg,
                       float* __restrict__ pblk, int* __restrict__ deg,
                       int NF, int N){
    int i = blockIdx.x*256 + threadIdx.x;
    if (i < NF){
        xb[i] = (u16)f2bf1(x[i]);
        agg[i] = -INFINITY;
    }
    if (i < N) deg[i] = 0;
    if (i < PB_TOT){
        pblk[i] = (i >= 1088 && i < 5184) ? -INFINITY : 0.f;
    }
}

__global__ void k_hist(const int* __restrict__ edst, int* __restrict__ deg, int E){
    int e = blockIdx.x*256 + threadIdx.x;
    if (e < E) atomicAdd(&deg[edst[e]], 1);
}

__global__ __launch_bounds__(1024) void k_scan(const int* __restrict__ deg,
                                               int* __restrict__ cursor, int N){
    __shared__ int buf[1024];
    __shared__ int carry;
    int tid = threadIdx.x;
    if (tid == 0) carry = 0;
    __syncthreads();
    for (int base = 0; base < N; base += 1024){
        int i = base + tid;
        int v = (i < N) ? deg[i] : 0;
        buf[tid] = v;
        __syncthreads();
        #pragma unroll
        for (int s = 1; s < 1024; s <<= 1){
            int a = (tid >= s) ? buf[tid - s] : 0;
            __syncthreads();
            buf[tid] += a;
            __syncthreads();
        }
        int inc = buf[tid] + carry;
        if (i < N) cursor[i] = inc - v;
        __syncthreads();
        if (tid == 1023) carry = inc;
        __syncthreads();
    }
}

__global__ void k_scatter(const int* __restrict__ esrc, const int* __restrict__ edst,
                          int* __restrict__ cursor, int2* __restrict__ ep, int E){
    int e = blockIdx.x*256 + threadIdx.x;
    if (e < E){
        int d = edst[e];
        int pos = atomicAdd(&cursor[d], 1);
        ep[pos] = make_int2(esrc[e], d);
    }
}

// Node GEMM -> PQ table. FMT=0: bf16 out; FMT=1: f16 out.
// PQ[n][c]: c<WC -> P=x@(Wtop-Wbot)+bias, c>=WC -> Q=x@Wbot.
template<int COUT, int FMT>
__global__ __launch_bounds__(256) void k_ngemm(
    const u16* __restrict__ xin, const float* __restrict__ Wsrc,
    const float* __restrict__ bias, u16* __restrict__ PQ, int N)
{
    const int WC = COUT/2;
    __shared__ u16 Wt[COUT*64];
    __shared__ u16 At[64*64];
    int tid = threadIdx.x;
    for (int i = tid; i < COUT*64; i += 256){
        int c = i >> 6, k = i & 63;
        float w = (c < WC) ? (Wsrc[k*WC + c] - Wsrc[(64+k)*WC + c])
                           : Wsrc[(64+k)*WC + (c - WC)];
        Wt[swz64(c, k)] = (u16)f2bf1(w);
    }
    int t = blockIdx.x;
    for (int i = tid; i < 512; i += 256){
        int row = i >> 3, ck = i & 7;
        int node = t*64 + row;
        uint4 v;
        if (node < N) v = *(const uint4*)(xin + (size_t)node*64 + ck*8);
        else { v.x = v.y = v.z = v.w = 0u; }
        *(uint4*)&At[swz64(row, ck*8)] = v;
    }
    __syncthreads();
    int lane = tid & 63, wave = tid >> 6;
    int lg = lane >> 4, lr = lane & 15;
    int row = wave*16 + lr;
    bf16x8 bfr[2];
    #pragma unroll
    for (int kt = 0; kt < 2; kt++)
        bfr[kt] = *(const bf16x8*)&At[swz64(row, kt*32 + lg*8)];
    int node = t*64 + wave*16 + lr;
    #pragma unroll
    for (int mt = 0; mt < COUT/16; mt++){
        f32x4 acc = {0.f,0.f,0.f,0.f};
        #pragma unroll
        for (int kt = 0; kt < 2; kt++){
            bf16x8 af = *(const bf16x8*)&Wt[swz64(mt*16 + lr, kt*32 + lg*8)];
            acc = mfma16(af, bfr[kt], acc);
        }
        int ch = mt*16 + lg*4;
        float r[4] = {acc[0], acc[1], acc[2], acc[3]};
        if (ch < WC){
            float4 bb = *(const float4*)(bias + ch);
            r[0] += bb.x; r[1] += bb.y; r[2] += bb.z; r[3] += bb.w;
        }
        if (node < N){
            us4 w4;
            #pragma unroll
            for (int j = 0; j < 4; j++){
                if (FMT){
                    f16 hf = (f16)r[j];
                    w4[j] = __builtin_bit_cast(u16, hf);
                } else {
                    w4[j] = (u16)f2bf1(r[j]);
                }
            }
            *(us4*)(PQ + (size_t)node*COUT + ch) = w4;
        }
    }
}

// pass1p: pull BN1a stats from f16 PQ1. lane handles ch {2*lane, 2*lane+1}.
__global__ __launch_bounds__(256) void k_pass1p(
    const u16* __restrict__ PQ1, const int2* __restrict__ ep,
    const int* __restrict__ cursor, const int* __restrict__ deg,
    float* __restrict__ pblk, int N)
{
    int tid = threadIdx.x;
    int lane = tid & 63, wave = tid >> 6;
    float s0 = 0.f, s1 = 0.f, q0 = 0.f, q1 = 0.f;
    const int* epi = (const int*)ep;

    for (int n = blockIdx.x*4 + wave; n < N; n += gridDim.x*4){
        int d  = deg[n];
        int r0 = cursor[n] - d;
        f16x2 pv = *(const f16x2*)(PQ1 + (size_t)n*256 + 2*lane);
        int src = (d > 0) ? epi[2*r0] : 0;
        for (int i = 0; i < d; ++i){
            int srcn = (i + 1 < d) ? epi[2*(r0 + i + 1)] : 0;
            f16x2 qv = *(const f16x2*)(PQ1 + (size_t)src*256 + 128 + 2*lane);
            f16x2 hv = pv + qv;
            float h0 = fmaxf((float)hv[0], 0.f);
            float h1 = fmaxf((float)hv[1], 0.f);
            s0 += h0; q0 = fmaf(h0, h0, q0);
            s1 += h1; q1 = fmaf(h1, h1, q1);
            src = srcn;
        }
    }
    __shared__ float bS0[256], bS1[256], bQ0[256], bQ1[256];
    bS0[tid] = s0; bS1[tid] = s1; bQ0[tid] = q0; bQ1[tid] = q1;
    __syncthreads();
    if (wave == 0){
        float a0 = bS0[lane] + bS0[64+lane] + bS0[128+lane] + bS0[192+lane];
        float a1 = bS1[lane] + bS1[64+lane] + bS1[128+lane] + bS1[192+lane];
        float c0 = bQ0[lane] + bQ0[64+lane] + bQ0[128+lane] + bQ0[192+lane];
        float c1 = bQ1[lane] + bQ1[64+lane] + bQ1[128+lane] + bQ1[192+lane];
        atomicAdd(&pblk[2*lane],       a0);
        atomicAdd(&pblk[2*lane + 1],   a1);
        atomicAdd(&pblk[128 + 2*lane],     c0);
        atomicAdd(&pblk[128 + 2*lane + 1], c1);
    }
}

__global__ void k_fold1(const float* __restrict__ g1a, const float* __restrict__ bt1a,
                        const float* __restrict__ W1b, const float* __restrict__ b1b,
                        float* __restrict__ pblk, float fE)
{
    __shared__ float tS[128];
    int tid = threadIdx.x;
    if (tid < 128){
        float m = pblk[tid] * fE;
        float q = pblk[128 + tid] * fE;
        float v = fmaxf(q - m*m, 0.f);
        float s = g1a[tid] * rsqrtf(v + EPSBN);
        float t = bt1a[tid] - m*s;
        pblk[512 + tid] = s;
        pblk[640 + tid] = t;
        tS[tid] = t;
    }
    __syncthreads();
    if (tid < 64){
        float acc = b1b[tid];
        for (int k = 0; k < 128; k++) acc = fmaf(tS[k], W1b[k*64 + tid], acc);
        pblk[768 + tid] = acc;
    }
}

// pass2p: pull GEMM-b with packed f16 + v_dot2_f32_f16.
// lane = output channel c; wh[kk] = f16 pair of folded column entries.
// Per edge: packed add+relu of (P,Q) pair, then 64x {readlane + fdot2}.
__global__ __launch_bounds__(256) void k_pass2p(
    const u16* __restrict__ PQ1, const int2* __restrict__ ep,
    const int* __restrict__ cursor, const int* __restrict__ deg,
    const float* __restrict__ W1b,
    float* __restrict__ pblk, float* __restrict__ agg, int N)
{
    int tid = threadIdx.x;
    int lane = tid & 63, wave = tid >> 6;
    f16x2 wh[64];
    #pragma unroll
    for (int kk = 0; kk < 64; kk++){
        float w0 = pblk[512 + 2*kk]     * W1b[(2*kk)*64 + lane];
        float w1 = pblk[512 + 2*kk + 1] * W1b[(2*kk + 1)*64 + lane];
        f16x2 t; t[0] = (f16)w0; t[1] = (f16)w1;
        wh[kk] = t;
    }
    float bc = pblk[768 + lane];
    float runS = 0.f, runQ = 0.f;
    const int* epi = (const int*)ep;
    const f16x2 z2 = {(f16)0, (f16)0};

    for (int n = blockIdx.x*4 + wave; n < N; n += gridDim.x*4){
        int d  = deg[n];
        int r0 = cursor[n] - d;
        f16x2 pv = *(const f16x2*)(PQ1 + (size_t)n*256 + 2*lane);
        float mh = -INFINITY;
        int src = (d > 0) ? epi[2*r0] : 0;
        for (int i = 0; i < d; ++i){
            int srcn = (i + 1 < d) ? epi[2*(r0 + i + 1)] : 0;
            f16x2 qv = *(const f16x2*)(PQ1 + (size_t)src*256 + 128 + 2*lane);
            f16x2 hv = pv + qv;
            hv[0] = hv[0] > z2[0] ? hv[0] : z2[0];
            hv[1] = hv[1] > z2[1] ? hv[1] : z2[1];
            u32 hp = __builtin_bit_cast(u32, hv);
            float acc = 0.f;
            #pragma unroll
            for (int kk = 0; kk < 64; kk++){
                u32 hb = (u32)__shfl((int)hp, kk, 64);
#if HAS_FDOT2
                acc = __builtin_amdgcn_fdot2(__builtin_bit_cast(f16x2, hb), wh[kk], acc, false);
#else
                f16x2 hh = __builtin_bit_cast(f16x2, hb);
                acc = fmaf((float)hh[0], (float)wh[kk][0], acc);
                acc = fmaf((float)hh[1], (float)wh[kk][1], acc);
#endif
            }
            float hb1 = fmaxf(acc + bc, 0.f);
            runS += hb1;
            runQ = fmaf(hb1, hb1, runQ);
            mh = fmaxf(mh, hb1);
            src = srcn;
        }
        if (d > 0) agg[(size_t)n*64 + lane] = mh;
    }
    __shared__ float bS[256], bQ[256];
    bS[tid] = runS; bQ[tid] = runQ;
    __syncthreads();
    if (wave == 0){
        float s = bS[lane] + bS[64+lane] + bS[128+lane] + bS[192+lane];
        float q = bQ[lane] + bQ[64+lane] + bQ[128+lane] + bQ[192+lane];
        atomicAdd(&pblk[256 + lane], s);
        atomicAdd(&pblk[320 + lane], q);
    }
}

__global__ void k_fold_st(const float* __restrict__ g, const float* __restrict__ bt,
                          float* __restrict__ pblk, float fE, int so, int qo, int os, int ot)
{
    int tid = threadIdx.x;
    if (tid < 64){
        float m = pblk[so + tid] * fE;
        float q = pblk[qo + tid] * fE;
        float v = fmaxf(q - m*m, 0.f);
        float s = g[tid] * rsqrtf(v + EPSBN);
        pblk[os + tid] = s;
        pblk[ot + tid] = bt[tid] - m*s;
    }
}

// x1 = relu(bn1b(agg) or 0) -> x1b; reset agg to -inf for pass3p reuse.
__global__ void k_x1(float* __restrict__ agg, const float* __restrict__ pblk,
                     u16* __restrict__ x1b, int NF)
{
    int i = blockIdx.x*256 + threadIdx.x;
    if (i >= NF) return;
    int c = i & 63;
    float a = agg[i];
    float v = (a > -INFINITY) ? fmaf(a, pblk[832 + c], pblk[896 + c]) : 0.f;
    v = fmaxf(v, 0.f);
    x1b[i] = (u16)f2bf1(v);
    agg[i] = -INFINITY;
}

// pass3p: PULL-based conv2 (R10 verbatim; PQ2 stays bf16).
__global__ __launch_bounds__(256) void k_pass3p(
    const u16* __restrict__ PQ2, const int2* __restrict__ ep,
    const int* __restrict__ cursor, const int* __restrict__ deg,
    float* __restrict__ pblk, float* __restrict__ agg, int N)
{
    int tid = threadIdx.x;
    int lane = tid & 63, wave = tid >> 6;
    float runS = 0.f, runQ = 0.f;
    const int* epi = (const int*)ep;

    for (int n = blockIdx.x*4 + wave; n < N; n += gridDim.x*4){
        int d  = deg[n];
        int r0 = cursor[n] - d;
        float p = bf2f(PQ2[(size_t)n*128 + lane]);
        float mq = -INFINITY;
        int src = (d > 0) ? epi[2*r0] : 0;
        for (int i = 0; i < d; ++i){
            int srcn = (i + 1 < d) ? epi[2*(r0 + i + 1)] : 0;
            float q = bf2f(PQ2[(size_t)src*128 + 64 + lane]);
            mq = fmaxf(mq, q);
            float h = fmaxf(p + q, 0.f);
            runS += h;
            runQ = fmaf(h, h, runQ);
            src = srcn;
        }
        if (d > 0) agg[(size_t)n*64 + lane] = mq;
    }
    __shared__ float bS[256], bQ[256];
    bS[tid] = runS; bQ[tid] = runQ;
    __syncthreads();
    if (wave == 0){
        float s = bS[lane] + bS[64 + lane] + bS[128 + lane] + bS[192 + lane];
        float q = bQ[lane] + bQ[64 + lane] + bQ[128 + lane] + bQ[192 + lane];
        atomicAdd(&pblk[384 + lane], s);
        atomicAdd(&pblk[448 + lane], q);
    }
}

#define FUSE_NODES 128
__global__ __launch_bounds__(256) void k_fuse(const float* __restrict__ agg,
                                              const u16* __restrict__ x1b,
                                              const u16* __restrict__ PQ2,
                                              const int* __restrict__ batch,
                                              float* __restrict__ pblk, int N)
{
    int c = threadIdx.x & 63, r = threadIdx.x >> 6;
    int n0 = blockIdx.x*FUSE_NODES + r*(FUSE_NODES/4);
    if (n0 >= N) return;
    int n1 = n0 + FUSE_NODES/4; if (n1 > N) n1 = N;
    float s2c = pblk[960 + c], t2c = pblk[1024 + c];
    float gm = -INFINITY, gs = 0.f;
    int cur = batch[n0], cnt0 = 0;
    for (int n = n0; n < n1; ++n){
        int g = batch[n];
        if (g != cur){
            atomicMaxF(&pblk[1088 + cur*64 + c], gm);
            atomicAdd(&pblk[5184 + cur*64 + c], gs);
            if (c == 0) atomicAdd(&pblk[9280 + cur], (float)cnt0);
            gm = -INFINITY; gs = 0.f; cnt0 = 0; cur = g;
        }
        float a = agg[(size_t)n*64 + c];   // maxQ2 (or -inf if no in-edges)
        float v;
        if (a > -INFINITY){
            float p = bf2f(PQ2[(size_t)n*128 + c]);
            float pre = fmaxf(p + a, 0.f);
            v = fmaxf(fmaf(pre, s2c, t2c), 0.f);
        } else v = 0.f;
        float f = bf2f(x1b[(size_t)n*64 + c]) + v;
        gm = fmaxf(gm, f); gs += f; cnt0++;
    }
    atomicMaxF(&pblk[1088 + cur*64 + c], gm);
    atomicAdd(&pblk[5184 + cur*64 + c], gs);
    if (c == 0) atomicAdd(&pblk[9280 + cur], (float)cnt0);
}

__global__ void k_out(const float* __restrict__ pblk, float* __restrict__ out)
{
    int i = blockIdx.x*256 + threadIdx.x;
    if (i >= 64*128) return;
    int g = i >> 7, c = i & 127;
    float r;
    if (c < 64){
        float m = pblk[1088 + g*64 + c];
        r = (m > -INFINITY) ? m : 0.f;
    } else {
        float s = pblk[5184 + g*64 + (c - 64)];
        float n = pblk[9280 + g];
        r = s / fmaxf(n, 1.f);
    }
    out[i] = r;
}

extern "C" void kernel_launch(void* const* d_in, const int* in_sizes, int n_in,
                              void* d_out, int out_size, void* d_ws, size_t ws_size,
                              hipStream_t stream)
{
    const float* x    = (const float*)d_in[0];
    const int*   ei   = (const int*)  d_in[1];
    const int*   batch= (const int*)  d_in[2];
    const float* W1a  = (const float*)d_in[3];
    const float* b1a  = (const float*)d_in[4];
    const float* g1a  = (const float*)d_in[5];
    const float* bt1a = (const float*)d_in[6];
    const float* W1b  = (const float*)d_in[7];
    const float* b1b  = (const float*)d_in[8];
    const float* g1b  = (const float*)d_in[9];
    const float* bt1b = (const float*)d_in[10];
    const float* W2   = (const float*)d_in[11];
    const float* b2   = (const float*)d_in[12];
    const float* g2   = (const float*)d_in[13];
    const float* bt2  = (const float*)d_in[14];

    int N  = in_sizes[0] / 64;
    int E  = in_sizes[1] / 2;
    int NF = N * 64;

    char* ws = (char*)d_ws;
    size_t off = 0;
    auto alloc = [&](size_t bytes){ size_t o = off; off += (bytes + 255) & ~(size_t)255; return o; };
    u16*   xb    = (u16*)  (ws + alloc((size_t)NF*2));
    u16*   x1b   = (u16*)  (ws + alloc((size_t)NF*2));
    float* agg   = (float*)(ws + alloc((size_t)NF*4));
    float* pblk  = (float*)(ws + alloc((size_t)PB_TOT*4));
    int*   deg   = (int*)  (ws + alloc((size_t)N*4));
    int*   cursor= (int*)  (ws + alloc((size_t)N*4));
    int2*  ep    = (int2*) (ws + alloc((size_t)E*8));
    u16*   PQ1   = (u16*)  (ws + alloc((size_t)N*256*2));
    u16*   PQ2   = (u16*)  (ws + alloc((size_t)N*128*2));
    (void)ws_size;   // ~71MB << proven 237.7MB budget

    const int* esrc = ei;
    const int* edst = ei + E;
    int gElem  = (NF + 255) / 256;
    int gEdge  = (E + 255) / 256;
    int gNode  = (N + 63) / 64;
    int gPull  = ((N + 3) / 4) < 2048 ? ((N + 3) / 4) : 2048;
    float fE   = 1.f / (float)E;

    k_init        <<<gElem, 256, 0, stream>>>(x, xb, agg, pblk, deg, NF, N);
    k_hist        <<<gEdge, 256, 0, stream>>>(edst, deg, E);
    k_scan        <<<1, 1024, 0, stream>>>(deg, cursor, N);
    k_scatter     <<<gEdge, 256, 0, stream>>>(esrc, edst, cursor, ep, E);
    k_ngemm<256,1><<<gNode, 256, 0, stream>>>(xb, W1a, b1a, PQ1, N);
    k_pass1p      <<<gPull, 256, 0, stream>>>(PQ1, ep, cursor, deg, pblk, N);
    k_fold1       <<<1, 128, 0, stream>>>(g1a, bt1a, W1b, b1b, pblk, fE);
    k_pass2p      <<<gPull, 256, 0, stream>>>(PQ1, ep, cursor, deg, W1b, pblk, agg, N);
    k_fold_st     <<<1, 64, 0, stream>>>(g1b, bt1b, pblk, fE, 256, 320, 832, 896);
    k_x1          <<<gElem, 256, 0, stream>>>(agg, pblk, x1b, NF);
    k_ngemm<128,0><<<gNode, 256, 0, stream>>>(x1b, W2, b2, PQ2, N);
    k_pass3p      <<<gPull, 256, 0, stream>>>(PQ2, ep, cursor, deg, pblk, agg, N);
    k_fold_st     <<<1, 64, 0, stream>>>(g2, bt2, pblk, fE, 384, 448, 960, 1024);
    k_fuse        <<<(N + FUSE_NODES - 1)/FUSE_NODES, 256, 0, stream>>>(agg, x1b, PQ2, batch, pblk, N);
    k_out         <<<32, 256, 0, stream>>>(pblk, (float*)d_out);
}

// Round 14
// 1193.479 us; speedup vs baseline: 1.7765x; 1.0675x over previous
//
#include <hip/hip_runtime.h>
#include <math.h>

// GraphNet: 2x EdgeConv (E=800k, F=H=64) + BN folded/commuted + pooling.
// R14: pass2p dependency-chain fix. R13 went latency-bound (VALUBusy 20%):
// one serial 64-deep fdot2 chain/edge. Now 2 edges/iteration x 4 accumulators
// = 8 independent chains (16 deep each) + 2 loads in flight. Instruction
// count unchanged. Everything else R13-verbatim (1274us).

typedef unsigned short u16;
typedef unsigned int   u32;
typedef __bf16 bf16x8 __attribute__((ext_vector_type(8)));
typedef float  f32x4  __attribute__((ext_vector_type(4)));
typedef unsigned short us4 __attribute__((ext_vector_type(4)));
typedef _Float16 f16;
typedef f16 f16x2 __attribute__((ext_vector_type(2)));

#define EPSBN 1e-5f
#define PB_TOT 9344
// pblk: 0:stS1a[128] 128:stQ1a[128] 256:stS1b 320:stQ1b 384:stS2 448:stQ2
// 512:s1a[128] 640:t1a[128] 768:b1bF[64] 832:s1b 896:t1b 960:s2 1024:t2
// 1088:gmax[4096] 5184:gsum[4096] 9280:cnt[64]

#if __has_builtin(__builtin_amdgcn_fdot2)
#define HAS_FDOT2 1
#else
#define HAS_FDOT2 0
#endif

__device__ __forceinline__ u32 f2bf1(float f){
    u32 u = __float_as_uint(f);
    return (u + 0x7FFFu + ((u >> 16) & 1u)) >> 16;
}
__device__ __forceinline__ float bf2f(u16 b){
    return __uint_as_float(((u32)b) << 16);
}
__device__ __forceinline__ void atomicMaxF(float* a, float v){
    if (v >= 0.f) atomicMax((int*)a, __float_as_int(v));
    else          atomicMin((u32*)a, __float_as_uint(v));
}
__device__ __forceinline__ int swz64(int row, int k){
    return row*64 + (k ^ ((row & 7) << 3));
}
__device__ __forceinline__ f32x4 mfma16(bf16x8 a, bf16x8 b, f32x4 c){
    return __builtin_amdgcn_mfma_f32_16x16x32_bf16(a, b, c, 0, 0, 0);
}
__device__ __forceinline__ float fdot2f(u32 h, f16x2 w, float acc){
#if HAS_FDOT2
    return __builtin_amdgcn_fdot2(__builtin_bit_cast(f16x2, h), w, acc, false);
#else
    f16x2 hh = __builtin_bit_cast(f16x2, h);
    acc = fmaf((float)hh[0], (float)w[0], acc);
    return fmaf((float)hh[1], (float)w[1], acc);
#endif
}

__global__ void k_init(const float* __restrict__ x, u16* __restrict__ xb,
                       float* __restrict__ agg,
                       float* __restrict__ pblk, int* __restrict__ deg,
                       int NF, int N){
    int i = blockIdx.x*256 + threadIdx.x;
    if (i < NF){
        xb[i] = (u16)f2bf1(x[i]);
        agg[i] = -INFINITY;
    }
    if (i < N) deg[i] = 0;
    if (i < PB_TOT){
        pblk[i] = (i >= 1088 && i < 5184) ? -INFINITY : 0.f;
    }
}

__global__ void k_hist(const int* __restrict__ edst, int* __restrict__ deg, int E){
    int e = blockIdx.x*256 + threadIdx.x;
    if (e < E) atomicAdd(&deg[edst[e]], 1);
}

__global__ __launch_bounds__(1024) void k_scan(const int* __restrict__ deg,
                                               int* __restrict__ cursor, int N){
    __shared__ int buf[1024];
    __shared__ int carry;
    int tid = threadIdx.x;
    if (tid == 0) carry = 0;
    __syncthreads();
    for (int base = 0; base < N; base += 1024){
        int i = base + tid;
        int v = (i < N) ? deg[i] : 0;
        buf[tid] = v;
        __syncthreads();
        #pragma unroll
        for (int s = 1; s < 1024; s <<= 1){
            int a = (tid >= s) ? buf[tid - s] : 0;
            __syncthreads();
            buf[tid] += a;
            __syncthreads();
        }
        int inc = buf[tid] + carry;
        if (i < N) cursor[i] = inc - v;
        __syncthreads();
        if (tid == 1023) carry = inc;
        __syncthreads();
    }
}

__global__ void k_scatter(const int* __restrict__ esrc, const int* __restrict__ edst,
                          int* __restrict__ cursor, int2* __restrict__ ep, int E){
    int e = blockIdx.x*256 + threadIdx.x;
    if (e < E){
        int d = edst[e];
        int pos = atomicAdd(&cursor[d], 1);
        ep[pos] = make_int2(esrc[e], d);
    }
}

// Node GEMM -> PQ table. FMT=0: bf16 out; FMT=1: f16 out.
template<int COUT, int FMT>
__global__ __launch_bounds__(256) void k_ngemm(
    const u16* __restrict__ xin, const float* __restrict__ Wsrc,
    const float* __restrict__ bias, u16* __restrict__ PQ, int N)
{
    const int WC = COUT/2;
    __shared__ u16 Wt[COUT*64];
    __shared__ u16 At[64*64];
    int tid = threadIdx.x;
    for (int i = tid; i < COUT*64; i += 256){
        int c = i >> 6, k = i & 63;
        float w = (c < WC) ? (Wsrc[k*WC + c] - Wsrc[(64+k)*WC + c])
                           : Wsrc[(64+k)*WC + (c - WC)];
        Wt[swz64(c, k)] = (u16)f2bf1(w);
    }
    int t = blockIdx.x;
    for (int i = tid; i < 512; i += 256){
        int row = i >> 3, ck = i & 7;
        int node = t*64 + row;
        uint4 v;
        if (node < N) v = *(const uint4*)(xin + (size_t)node*64 + ck*8);
        else { v.x = v.y = v.z = v.w = 0u; }
        *(uint4*)&At[swz64(row, ck*8)] = v;
    }
    __syncthreads();
    int lane = tid & 63, wave = tid >> 6;
    int lg = lane >> 4, lr = lane & 15;
    int row = wave*16 + lr;
    bf16x8 bfr[2];
    #pragma unroll
    for (int kt = 0; kt < 2; kt++)
        bfr[kt] = *(const bf16x8*)&At[swz64(row, kt*32 + lg*8)];
    int node = t*64 + wave*16 + lr;
    #pragma unroll
    for (int mt = 0; mt < COUT/16; mt++){
        f32x4 acc = {0.f,0.f,0.f,0.f};
        #pragma unroll
        for (int kt = 0; kt < 2; kt++){
            bf16x8 af = *(const bf16x8*)&Wt[swz64(mt*16 + lr, kt*32 + lg*8)];
            acc = mfma16(af, bfr[kt], acc);
        }
        int ch = mt*16 + lg*4;
        float r[4] = {acc[0], acc[1], acc[2], acc[3]};
        if (ch < WC){
            float4 bb = *(const float4*)(bias + ch);
            r[0] += bb.x; r[1] += bb.y; r[2] += bb.z; r[3] += bb.w;
        }
        if (node < N){
            us4 w4;
            #pragma unroll
            for (int j = 0; j < 4; j++){
                if (FMT){
                    f16 hf = (f16)r[j];
                    w4[j] = __builtin_bit_cast(u16, hf);
                } else {
                    w4[j] = (u16)f2bf1(r[j]);
                }
            }
            *(us4*)(PQ + (size_t)node*COUT + ch) = w4;
        }
    }
}

// pass1p: pull BN1a stats from f16 PQ1. lane handles ch {2*lane, 2*lane+1}.
__global__ __launch_bounds__(256) void k_pass1p(
    const u16* __restrict__ PQ1, const int2* __restrict__ ep,
    const int* __restrict__ cursor, const int* __restrict__ deg,
    float* __restrict__ pblk, int N)
{
    int tid = threadIdx.x;
    int lane = tid & 63, wave = tid >> 6;
    float s0 = 0.f, s1 = 0.f, q0 = 0.f, q1 = 0.f;
    const int* epi = (const int*)ep;

    for (int n = blockIdx.x*4 + wave; n < N; n += gridDim.x*4){
        int d  = deg[n];
        int r0 = cursor[n] - d;
        f16x2 pv = *(const f16x2*)(PQ1 + (size_t)n*256 + 2*lane);
        int src = (d > 0) ? epi[2*r0] : 0;
        for (int i = 0; i < d; ++i){
            int srcn = (i + 1 < d) ? epi[2*(r0 + i + 1)] : 0;
            f16x2 qv = *(const f16x2*)(PQ1 + (size_t)src*256 + 128 + 2*lane);
            f16x2 hv = pv + qv;
            float h0 = fmaxf((float)hv[0], 0.f);
            float h1 = fmaxf((float)hv[1], 0.f);
            s0 += h0; q0 = fmaf(h0, h0, q0);
            s1 += h1; q1 = fmaf(h1, h1, q1);
            src = srcn;
        }
    }
    __shared__ float bS0[256], bS1[256], bQ0[256], bQ1[256];
    bS0[tid] = s0; bS1[tid] = s1; bQ0[tid] = q0; bQ1[tid] = q1;
    __syncthreads();
    if (wave == 0){
        float a0 = bS0[lane] + bS0[64+lane] + bS0[128+lane] + bS0[192+lane];
        float a1 = bS1[lane] + bS1[64+lane] + bS1[128+lane] + bS1[192+lane];
        float c0 = bQ0[lane] + bQ0[64+lane] + bQ0[128+lane] + bQ0[192+lane];
        float c1 = bQ1[lane] + bQ1[64+lane] + bQ1[128+lane] + bQ1[192+lane];
        atomicAdd(&pblk[2*lane],       a0);
        atomicAdd(&pblk[2*lane + 1],   a1);
        atomicAdd(&pblk[128 + 2*lane],     c0);
        atomicAdd(&pblk[128 + 2*lane + 1], c1);
    }
}

__global__ void k_fold1(const float* __restrict__ g1a, const float* __restrict__ bt1a,
                        const float* __restrict__ W1b, const float* __restrict__ b1b,
                        float* __restrict__ pblk, float fE)
{
    __shared__ float tS[128];
    int tid = threadIdx.x;
    if (tid < 128){
        float m = pblk[tid] * fE;
        float q = pblk[128 + tid] * fE;
        float v = fmaxf(q - m*m, 0.f);
        float s = g1a[tid] * rsqrtf(v + EPSBN);
        float t = bt1a[tid] - m*s;
        pblk[512 + tid] = s;
        pblk[640 + tid] = t;
        tS[tid] = t;
    }
    __syncthreads();
    if (tid < 64){
        float acc = b1b[tid];
        for (int k = 0; k < 128; k++) acc = fmaf(tS[k], W1b[k*64 + tid], acc);
        pblk[768 + tid] = acc;
    }
}

// pass2p: pull GEMM-b, 2 edges/iter x 4 accumulators = 8 independent fdot2
// chains. lane = output channel; wh[kk] = folded f16 column pair.
__global__ __launch_bounds__(256) void k_pass2p(
    const u16* __restrict__ PQ1, const int2* __restrict__ ep,
    const int* __restrict__ cursor, const int* __restrict__ deg,
    const float* __restrict__ W1b,
    float* __restrict__ pblk, float* __restrict__ agg, int N)
{
    int tid = threadIdx.x;
    int lane = tid & 63, wave = tid >> 6;
    f16x2 wh[64];
    #pragma unroll
    for (int kk = 0; kk < 64; kk++){
        float w0 = pblk[512 + 2*kk]     * W1b[(2*kk)*64 + lane];
        float w1 = pblk[512 + 2*kk + 1] * W1b[(2*kk + 1)*64 + lane];
        f16x2 t; t[0] = (f16)w0; t[1] = (f16)w1;
        wh[kk] = t;
    }
    float bc = pblk[768 + lane];
    float runS = 0.f, runQ = 0.f;
    const int* epi = (const int*)ep;
    const f16 z0 = (f16)0;

    for (int n = blockIdx.x*4 + wave; n < N; n += gridDim.x*4){
        int d  = deg[n];
        int r0 = cursor[n] - d;
        f16x2 pv = *(const f16x2*)(PQ1 + (size_t)n*256 + 2*lane);
        float mh = -INFINITY;
        int i = 0;
        for (; i + 1 < d; i += 2){
            int sA = epi[2*(r0 + i)];
            int sB = epi[2*(r0 + i + 1)];
            f16x2 qA = *(const f16x2*)(PQ1 + (size_t)sA*256 + 128 + 2*lane);
            f16x2 qB = *(const f16x2*)(PQ1 + (size_t)sB*256 + 128 + 2*lane);
            f16x2 hA = pv + qA, hB = pv + qB;
            hA[0] = hA[0] > z0 ? hA[0] : z0;  hA[1] = hA[1] > z0 ? hA[1] : z0;
            hB[0] = hB[0] > z0 ? hB[0] : z0;  hB[1] = hB[1] > z0 ? hB[1] : z0;
            u32 hpA = __builtin_bit_cast(u32, hA);
            u32 hpB = __builtin_bit_cast(u32, hB);
            float aA[4] = {0.f,0.f,0.f,0.f};
            float aB[4] = {0.f,0.f,0.f,0.f};
            #pragma unroll
            for (int kk = 0; kk < 64; kk++){
                u32 xA = (u32)__shfl((int)hpA, kk, 64);
                u32 xB = (u32)__shfl((int)hpB, kk, 64);
                aA[kk & 3] = fdot2f(xA, wh[kk], aA[kk & 3]);
                aB[kk & 3] = fdot2f(xB, wh[kk], aB[kk & 3]);
            }
            float hbA = fmaxf((aA[0]+aA[1]) + (aA[2]+aA[3]) + bc, 0.f);
            float hbB = fmaxf((aB[0]+aB[1]) + (aB[2]+aB[3]) + bc, 0.f);
            runS += hbA + hbB;
            runQ = fmaf(hbA, hbA, runQ);
            runQ = fmaf(hbB, hbB, runQ);
            mh = fmaxf(mh, fmaxf(hbA, hbB));
        }
        if (i < d){
            int sA = epi[2*(r0 + i)];
            f16x2 qA = *(const f16x2*)(PQ1 + (size_t)sA*256 + 128 + 2*lane);
            f16x2 hA = pv + qA;
            hA[0] = hA[0] > z0 ? hA[0] : z0;  hA[1] = hA[1] > z0 ? hA[1] : z0;
            u32 hpA = __builtin_bit_cast(u32, hA);
            float aA[4] = {0.f,0.f,0.f,0.f};
            #pragma unroll
            for (int kk = 0; kk < 64; kk++){
                u32 xA = (u32)__shfl((int)hpA, kk, 64);
                aA[kk & 3] = fdot2f(xA, wh[kk], aA[kk & 3]);
            }
            float hbA = fmaxf((aA[0]+aA[1]) + (aA[2]+aA[3]) + bc, 0.f);
            runS += hbA;
            runQ = fmaf(hbA, hbA, runQ);
            mh = fmaxf(mh, hbA);
        }
        if (d > 0) agg[(size_t)n*64 + lane] = mh;
    }
    __shared__ float bS[256], bQ[256];
    bS[tid] = runS; bQ[tid] = runQ;
    __syncthreads();
    if (wave == 0){
        float s = bS[lane] + bS[64+lane] + bS[128+lane] + bS[192+lane];
        float q = bQ[lane] + bQ[64+lane] + bQ[128+lane] + bQ[192+lane];
        atomicAdd(&pblk[256 + lane], s);
        atomicAdd(&pblk[320 + lane], q);
    }
}

__global__ void k_fold_st(const float* __restrict__ g, const float* __restrict__ bt,
                          float* __restrict__ pblk, float fE, int so, int qo, int os, int ot)
{
    int tid = threadIdx.x;
    if (tid < 64){
        float m = pblk[so + tid] * fE;
        float q = pblk[qo + tid] * fE;
        float v = fmaxf(q - m*m, 0.f);
        float s = g[tid] * rsqrtf(v + EPSBN);
        pblk[os + tid] = s;
        pblk[ot + tid] = bt[tid] - m*s;
    }
}

// x1 = relu(bn1b(agg) or 0) -> x1b; reset agg to -inf for pass3p reuse.
__global__ void k_x1(float* __restrict__ agg, const float* __restrict__ pblk,
                     u16* __restrict__ x1b, int NF)
{
    int i = blockIdx.x*256 + threadIdx.x;
    if (i >= NF) return;
    int c = i & 63;
    float a = agg[i];
    float v = (a > -INFINITY) ? fmaf(a, pblk[832 + c], pblk[896 + c]) : 0.f;
    v = fmaxf(v, 0.f);
    x1b[i] = (u16)f2bf1(v);
    agg[i] = -INFINITY;
}

// pass3p: PULL-based conv2 (R10 verbatim; PQ2 stays bf16).
__global__ __launch_bounds__(256) void k_pass3p(
    const u16* __restrict__ PQ2, const int2* __restrict__ ep,
    const int* __restrict__ cursor, const int* __restrict__ deg,
    float* __restrict__ pblk, float* __restrict__ agg, int N)
{
    int tid = threadIdx.x;
    int lane = tid & 63, wave = tid >> 6;
    float runS = 0.f, runQ = 0.f;
    const int* epi = (const int*)ep;

    for (int n = blockIdx.x*4 + wave; n < N; n += gridDim.x*4){
        int d  = deg[n];
        int r0 = cursor[n] - d;
        float p = bf2f(PQ2[(size_t)n*128 + lane]);
        float mq = -INFINITY;
        int src = (d > 0) ? epi[2*r0] : 0;
        for (int i = 0; i < d; ++i){
            int srcn = (i + 1 < d) ? epi[2*(r0 + i + 1)] : 0;
            float q = bf2f(PQ2[(size_t)src*128 + 64 + lane]);
            mq = fmaxf(mq, q);
            float h = fmaxf(p + q, 0.f);
            runS += h;
            runQ = fmaf(h, h, runQ);
            src = srcn;
        }
        if (d > 0) agg[(size_t)n*64 + lane] = mq;
    }
    __shared__ float bS[256], bQ[256];
    bS[tid] = runS; bQ[tid] = runQ;
    __syncthreads();
    if (wave == 0){
        float s = bS[lane] + bS[64 + lane] + bS[128 + lane] + bS[192 + lane];
        float q = bQ[lane] + bQ[64 + lane] + bQ[128 + lane] + bQ[192 + lane];
        atomicAdd(&pblk[384 + lane], s);
        atomicAdd(&pblk[448 + lane], q);
    }
}

#define FUSE_NODES 128
__global__ __launch_bounds__(256) void k_fuse(const float* __restrict__ agg,
                                              const u16* __restrict__ x1b,
                                              const u16* __restrict__ PQ2,
                                              const int* __restrict__ batch,
                                              float* __restrict__ pblk, int N)
{
    int c = threadIdx.x & 63, r = threadIdx.x >> 6;
    int n0 = blockIdx.x*FUSE_NODES + r*(FUSE_NODES/4);
    if (n0 >= N) return;
    int n1 = n0 + FUSE_NODES/4; if (n1 > N) n1 = N;
    float s2c = pblk[960 + c], t2c = pblk[1024 + c];
    float gm = -INFINITY, gs = 0.f;
    int cur = batch[n0], cnt0 = 0;
    for (int n = n0; n < n1; ++n){
        int g = batch[n];
        if (g != cur){
            atomicMaxF(&pblk[1088 + cur*64 + c], gm);
            atomicAdd(&pblk[5184 + cur*64 + c], gs);
            if (c == 0) atomicAdd(&pblk[9280 + cur], (float)cnt0);
            gm = -INFINITY; gs = 0.f; cnt0 = 0; cur = g;
        }
        float a = agg[(size_t)n*64 + c];   // maxQ2 (or -inf if no in-edges)
        float v;
        if (a > -INFINITY){
            float p = bf2f(PQ2[(size_t)n*128 + c]);
            float pre = fmaxf(p + a, 0.f);
            v = fmaxf(fmaf(pre, s2c, t2c), 0.f);
        } else v = 0.f;
        float f = bf2f(x1b[(size_t)n*64 + c]) + v;
        gm = fmaxf(gm, f); gs += f; cnt0++;
    }
    atomicMaxF(&pblk[1088 + cur*64 + c], gm);
    atomicAdd(&pblk[5184 + cur*64 + c], gs);
    if (c == 0) atomicAdd(&pblk[9280 + cur], (float)cnt0);
}

__global__ void k_out(const float* __restrict__ pblk, float* __restrict__ out)
{
    int i = blockIdx.x*256 + threadIdx.x;
    if (i >= 64*128) return;
    int g = i >> 7, c = i & 127;
    float r;
    if (c < 64){
        float m = pblk[1088 + g*64 + c];
        r = (m > -INFINITY) ? m : 0.f;
    } else {
        float s = pblk[5184 + g*64 + (c - 64)];
        float n = pblk[9280 + g];
        r = s / fmaxf(n, 1.f);
    }
    out[i] = r;
}

extern "C" void kernel_launch(void* const* d_in, const int* in_sizes, int n_in,
                              void* d_out, int out_size, void* d_ws, size_t ws_size,
                              hipStream_t stream)
{
    const float* x    = (const float*)d_in[0];
    const int*   ei   = (const int*)  d_in[1];
    const int*   batch= (const int*)  d_in[2];
    const float* W1a  = (const float*)d_in[3];
    const float* b1a  = (const float*)d_in[4];
    const float* g1a  = (const float*)d_in[5];
    const float* bt1a = (const float*)d_in[6];
    const float* W1b  = (const float*)d_in[7];
    const float* b1b  = (const float*)d_in[8];
    const float* g1b  = (const float*)d_in[9];
    const float* bt1b = (const float*)d_in[10];
    const float* W2   = (const float*)d_in[11];
    const float* b2   = (const float*)d_in[12];
    const float* g2   = (const float*)d_in[13];
    const float* bt2  = (const float*)d_in[14];

    int N  = in_sizes[0] / 64;
    int E  = in_sizes[1] / 2;
    int NF = N * 64;

    char* ws = (char*)d_ws;
    size_t off = 0;
    auto alloc = [&](size_t bytes){ size_t o = off; off += (bytes + 255) & ~(size_t)255; return o; };
    u16*   xb    = (u16*)  (ws + alloc((size_t)NF*2));
    u16*   x1b   = (u16*)  (ws + alloc((size_t)NF*2));
    float* agg   = (float*)(ws + alloc((size_t)NF*4));
    float* pblk  = (float*)(ws + alloc((size_t)PB_TOT*4));
    int*   deg   = (int*)  (ws + alloc((size_t)N*4));
    int*   cursor= (int*)  (ws + alloc((size_t)N*4));
    int2*  ep    = (int2*) (ws + alloc((size_t)E*8));
    u16*   PQ1   = (u16*)  (ws + alloc((size_t)N*256*2));
    u16*   PQ2   = (u16*)  (ws + alloc((size_t)N*128*2));
    (void)ws_size;   // ~71MB << proven 237.7MB budget

    const int* esrc = ei;
    const int* edst = ei + E;
    int gElem  = (NF + 255) / 256;
    int gEdge  = (E + 255) / 256;
    int gNode  = (N + 63) / 64;
    int gPull  = ((N + 3) / 4) < 2048 ? ((N + 3) / 4) : 2048;
    float fE   = 1.f / (float)E;

    k_init        <<<gElem, 256, 0, stream>>>(x, xb, agg, pblk, deg, NF, N);
    k_hist        <<<gEdge, 256, 0, stream>>>(edst, deg, E);
    k_scan        <<<1, 1024, 0, stream>>>(deg, cursor, N);
    k_scatter     <<<gEdge, 256, 0, stream>>>(esrc, edst, cursor, ep, E);
    k_ngemm<256,1><<<gNode, 256, 0, stream>>>(xb, W1a, b1a, PQ1, N);
    k_pass1p      <<<gPull, 256, 0, stream>>>(PQ1, ep, cursor, deg, pblk, N);
    k_fold1       <<<1, 128, 0, stream>>>(g1a, bt1a, W1b, b1b, pblk, fE);
    k_pass2p      <<<gPull, 256, 0, stream>>>(PQ1, ep, cursor, deg, W1b, pblk, agg, N);
    k_fold_st     <<<1, 64, 0, stream>>>(g1b, bt1b, pblk, fE, 256, 320, 832, 896);
    k_x1          <<<gElem, 256, 0, stream>>>(agg, pblk, x1b, NF);
    k_ngemm<128,0><<<gNode, 256, 0, stream>>>(x1b, W2, b2, PQ2, N);
    k_pass3p      <<<gPull, 256, 0, stream>>>(PQ2, ep, cursor, deg, pblk, agg, N);
    k_fold_st     <<<1, 64, 0, stream>>>(g2, bt2, pblk, fE, 384, 448, 960, 1024);
    k_fuse        <<<(N + FUSE_NODES - 1)/FUSE_NODES, 256, 0, stream>>>(agg, x1b, PQ2, batch, pblk, N);
    k_out         <<<32, 256, 0, stream>>>(pblk, (float*)d_out);
}

// Round 15
// 870.004 us; speedup vs baseline: 2.4370x; 1.3718x over previous
//
#include <hip/hip_runtime.h>
#include <math.h>

// GraphNet: 2x EdgeConv (E=800k, F=H=64) + BN folded/commuted + pooling.
// R15: pass2p broadcast moved off the LDS pipe. R14 was shuffle-bound:
// __shfl(x,kk,64) = ds_bpermute (LDS pipe), 64/edge = 51.2M ops ~ 500us.
// The broadcast is wave-uniform -> v_readlane (scalar path) is exact:
// __builtin_amdgcn_readlane + fdot2(SGPR src). Everything else R14-verbatim.

typedef unsigned short u16;
typedef unsigned int   u32;
typedef __bf16 bf16x8 __attribute__((ext_vector_type(8)));
typedef float  f32x4  __attribute__((ext_vector_type(4)));
typedef unsigned short us4 __attribute__((ext_vector_type(4)));
typedef _Float16 f16;
typedef f16 f16x2 __attribute__((ext_vector_type(2)));

#define EPSBN 1e-5f
#define PB_TOT 9344
// pblk: 0:stS1a[128] 128:stQ1a[128] 256:stS1b 320:stQ1b 384:stS2 448:stQ2
// 512:s1a[128] 640:t1a[128] 768:b1bF[64] 832:s1b 896:t1b 960:s2 1024:t2
// 1088:gmax[4096] 5184:gsum[4096] 9280:cnt[64]

#if __has_builtin(__builtin_amdgcn_fdot2)
#define HAS_FDOT2 1
#else
#define HAS_FDOT2 0
#endif
#if __has_builtin(__builtin_amdgcn_readlane)
#define RLANE(v, l) ((u32)__builtin_amdgcn_readlane((int)(v), (l)))
#else
#define RLANE(v, l) ((u32)__shfl((int)(v), (l), 64))
#endif

__device__ __forceinline__ u32 f2bf1(float f){
    u32 u = __float_as_uint(f);
    return (u + 0x7FFFu + ((u >> 16) & 1u)) >> 16;
}
__device__ __forceinline__ float bf2f(u16 b){
    return __uint_as_float(((u32)b) << 16);
}
__device__ __forceinline__ void atomicMaxF(float* a, float v){
    if (v >= 0.f) atomicMax((int*)a, __float_as_int(v));
    else          atomicMin((u32*)a, __float_as_uint(v));
}
__device__ __forceinline__ int swz64(int row, int k){
    return row*64 + (k ^ ((row & 7) << 3));
}
__device__ __forceinline__ f32x4 mfma16(bf16x8 a, bf16x8 b, f32x4 c){
    return __builtin_amdgcn_mfma_f32_16x16x32_bf16(a, b, c, 0, 0, 0);
}
__device__ __forceinline__ float fdot2f(u32 h, f16x2 w, float acc){
#if HAS_FDOT2
    return __builtin_amdgcn_fdot2(__builtin_bit_cast(f16x2, h), w, acc, false);
#else
    f16x2 hh = __builtin_bit_cast(f16x2, h);
    acc = fmaf((float)hh[0], (float)w[0], acc);
    return fmaf((float)hh[1], (float)w[1], acc);
#endif
}

__global__ void k_init(const float* __restrict__ x, u16* __restrict__ xb,
                       float* __restrict__ agg,
                       float* __restrict__ pblk, int* __restrict__ deg,
                       int NF, int N){
    int i = blockIdx.x*256 + threadIdx.x;
    if (i < NF){
        xb[i] = (u16)f2bf1(x[i]);
        agg[i] = -INFINITY;
    }
    if (i < N) deg[i] = 0;
    if (i < PB_TOT){
        pblk[i] = (i >= 1088 && i < 5184) ? -INFINITY : 0.f;
    }
}

__global__ void k_hist(const int* __restrict__ edst, int* __restrict__ deg, int E){
    int e = blockIdx.x*256 + threadIdx.x;
    if (e < E) atomicAdd(&deg[edst[e]], 1);
}

__global__ __launch_bounds__(1024) void k_scan(const int* __restrict__ deg,
                                               int* __restrict__ cursor, int N){
    __shared__ int buf[1024];
    __shared__ int carry;
    int tid = threadIdx.x;
    if (tid == 0) carry = 0;
    __syncthreads();
    for (int base = 0; base < N; base += 1024){
        int i = base + tid;
        int v = (i < N) ? deg[i] : 0;
        buf[tid] = v;
        __syncthreads();
        #pragma unroll
        for (int s = 1; s < 1024; s <<= 1){
            int a = (tid >= s) ? buf[tid - s] : 0;
            __syncthreads();
            buf[tid] += a;
            __syncthreads();
        }
        int inc = buf[tid] + carry;
        if (i < N) cursor[i] = inc - v;
        __syncthreads();
        if (tid == 1023) carry = inc;
        __syncthreads();
    }
}

__global__ void k_scatter(const int* __restrict__ esrc, const int* __restrict__ edst,
                          int* __restrict__ cursor, int2* __restrict__ ep, int E){
    int e = blockIdx.x*256 + threadIdx.x;
    if (e < E){
        int d = edst[e];
        int pos = atomicAdd(&cursor[d], 1);
        ep[pos] = make_int2(esrc[e], d);
    }
}

// Node GEMM -> PQ table. FMT=0: bf16 out; FMT=1: f16 out.
template<int COUT, int FMT>
__global__ __launch_bounds__(256) void k_ngemm(
    const u16* __restrict__ xin, const float* __restrict__ Wsrc,
    const float* __restrict__ bias, u16* __restrict__ PQ, int N)
{
    const int WC = COUT/2;
    __shared__ u16 Wt[COUT*64];
    __shared__ u16 At[64*64];
    int tid = threadIdx.x;
    for (int i = tid; i < COUT*64; i += 256){
        int c = i >> 6, k = i & 63;
        float w = (c < WC) ? (Wsrc[k*WC + c] - Wsrc[(64+k)*WC + c])
                           : Wsrc[(64+k)*WC + (c - WC)];
        Wt[swz64(c, k)] = (u16)f2bf1(w);
    }
    int t = blockIdx.x;
    for (int i = tid; i < 512; i += 256){
        int row = i >> 3, ck = i & 7;
        int node = t*64 + row;
        uint4 v;
        if (node < N) v = *(const uint4*)(xin + (size_t)node*64 + ck*8);
        else { v.x = v.y = v.z = v.w = 0u; }
        *(uint4*)&At[swz64(row, ck*8)] = v;
    }
    __syncthreads();
    int lane = tid & 63, wave = tid >> 6;
    int lg = lane >> 4, lr = lane & 15;
    int row = wave*16 + lr;
    bf16x8 bfr[2];
    #pragma unroll
    for (int kt = 0; kt < 2; kt++)
        bfr[kt] = *(const bf16x8*)&At[swz64(row, kt*32 + lg*8)];
    int node = t*64 + wave*16 + lr;
    #pragma unroll
    for (int mt = 0; mt < COUT/16; mt++){
        f32x4 acc = {0.f,0.f,0.f,0.f};
        #pragma unroll
        for (int kt = 0; kt < 2; kt++){
            bf16x8 af = *(const bf16x8*)&Wt[swz64(mt*16 + lr, kt*32 + lg*8)];
            acc = mfma16(af, bfr[kt], acc);
        }
        int ch = mt*16 + lg*4;
        float r[4] = {acc[0], acc[1], acc[2], acc[3]};
        if (ch < WC){
            float4 bb = *(const float4*)(bias + ch);
            r[0] += bb.x; r[1] += bb.y; r[2] += bb.z; r[3] += bb.w;
        }
        if (node < N){
            us4 w4;
            #pragma unroll
            for (int j = 0; j < 4; j++){
                if (FMT){
                    f16 hf = (f16)r[j];
                    w4[j] = __builtin_bit_cast(u16, hf);
                } else {
                    w4[j] = (u16)f2bf1(r[j]);
                }
            }
            *(us4*)(PQ + (size_t)node*COUT + ch) = w4;
        }
    }
}

// pass1p: pull BN1a stats from f16 PQ1. lane handles ch {2*lane, 2*lane+1}.
__global__ __launch_bounds__(256) void k_pass1p(
    const u16* __restrict__ PQ1, const int2* __restrict__ ep,
    const int* __restrict__ cursor, const int* __restrict__ deg,
    float* __restrict__ pblk, int N)
{
    int tid = threadIdx.x;
    int lane = tid & 63, wave = tid >> 6;
    float s0 = 0.f, s1 = 0.f, q0 = 0.f, q1 = 0.f;
    const int* epi = (const int*)ep;

    for (int n = blockIdx.x*4 + wave; n < N; n += gridDim.x*4){
        int d  = deg[n];
        int r0 = cursor[n] - d;
        f16x2 pv = *(const f16x2*)(PQ1 + (size_t)n*256 + 2*lane);
        int src = (d > 0) ? epi[2*r0] : 0;
        for (int i = 0; i < d; ++i){
            int srcn = (i + 1 < d) ? epi[2*(r0 + i + 1)] : 0;
            f16x2 qv = *(const f16x2*)(PQ1 + (size_t)src*256 + 128 + 2*lane);
            f16x2 hv = pv + qv;
            float h0 = fmaxf((float)hv[0], 0.f);
            float h1 = fmaxf((float)hv[1], 0.f);
            s0 += h0; q0 = fmaf(h0, h0, q0);
            s1 += h1; q1 = fmaf(h1, h1, q1);
            src = srcn;
        }
    }
    __shared__ float bS0[256], bS1[256], bQ0[256], bQ1[256];
    bS0[tid] = s0; bS1[tid] = s1; bQ0[tid] = q0; bQ1[tid] = q1;
    __syncthreads();
    if (wave == 0){
        float a0 = bS0[lane] + bS0[64+lane] + bS0[128+lane] + bS0[192+lane];
        float a1 = bS1[lane] + bS1[64+lane] + bS1[128+lane] + bS1[192+lane];
        float c0 = bQ0[lane] + bQ0[64+lane] + bQ0[128+lane] + bQ0[192+lane];
        float c1 = bQ1[lane] + bQ1[64+lane] + bQ1[128+lane] + bQ1[192+lane];
        atomicAdd(&pblk[2*lane],       a0);
        atomicAdd(&pblk[2*lane + 1],   a1);
        atomicAdd(&pblk[128 + 2*lane],     c0);
        atomicAdd(&pblk[128 + 2*lane + 1], c1);
    }
}

__global__ void k_fold1(const float* __restrict__ g1a, const float* __restrict__ bt1a,
                        const float* __restrict__ W1b, const float* __restrict__ b1b,
                        float* __restrict__ pblk, float fE)
{
    __shared__ float tS[128];
    int tid = threadIdx.x;
    if (tid < 128){
        float m = pblk[tid] * fE;
        float q = pblk[128 + tid] * fE;
        float v = fmaxf(q - m*m, 0.f);
        float s = g1a[tid] * rsqrtf(v + EPSBN);
        float t = bt1a[tid] - m*s;
        pblk[512 + tid] = s;
        pblk[640 + tid] = t;
        tS[tid] = t;
    }
    __syncthreads();
    if (tid < 64){
        float acc = b1b[tid];
        for (int k = 0; k < 128; k++) acc = fmaf(tS[k], W1b[k*64 + tid], acc);
        pblk[768 + tid] = acc;
    }
}

// pass2p: pull GEMM-b, 2 edges/iter x 4 accumulators; broadcast via
// v_readlane (scalar path — wave-uniform value) + fdot2 with SGPR src.
__global__ __launch_bounds__(256) void k_pass2p(
    const u16* __restrict__ PQ1, const int2* __restrict__ ep,
    const int* __restrict__ cursor, const int* __restrict__ deg,
    const float* __restrict__ W1b,
    float* __restrict__ pblk, float* __restrict__ agg, int N)
{
    int tid = threadIdx.x;
    int lane = tid & 63, wave = tid >> 6;
    f16x2 wh[64];
    #pragma unroll
    for (int kk = 0; kk < 64; kk++){
        float w0 = pblk[512 + 2*kk]     * W1b[(2*kk)*64 + lane];
        float w1 = pblk[512 + 2*kk + 1] * W1b[(2*kk + 1)*64 + lane];
        f16x2 t; t[0] = (f16)w0; t[1] = (f16)w1;
        wh[kk] = t;
    }
    float bc = pblk[768 + lane];
    float runS = 0.f, runQ = 0.f;
    const int* epi = (const int*)ep;
    const f16 z0 = (f16)0;

    for (int n = blockIdx.x*4 + wave; n < N; n += gridDim.x*4){
        int d  = deg[n];
        int r0 = cursor[n] - d;
        f16x2 pv = *(const f16x2*)(PQ1 + (size_t)n*256 + 2*lane);
        float mh = -INFINITY;
        int i = 0;
        for (; i + 1 < d; i += 2){
            int sA = epi[2*(r0 + i)];
            int sB = epi[2*(r0 + i + 1)];
            f16x2 qA = *(const f16x2*)(PQ1 + (size_t)sA*256 + 128 + 2*lane);
            f16x2 qB = *(const f16x2*)(PQ1 + (size_t)sB*256 + 128 + 2*lane);
            f16x2 hA = pv + qA, hB = pv + qB;
            hA[0] = hA[0] > z0 ? hA[0] : z0;  hA[1] = hA[1] > z0 ? hA[1] : z0;
            hB[0] = hB[0] > z0 ? hB[0] : z0;  hB[1] = hB[1] > z0 ? hB[1] : z0;
            u32 hpA = __builtin_bit_cast(u32, hA);
            u32 hpB = __builtin_bit_cast(u32, hB);
            float aA[4] = {0.f,0.f,0.f,0.f};
            float aB[4] = {0.f,0.f,0.f,0.f};
            #pragma unroll
            for (int kk = 0; kk < 64; kk++){
                u32 xA = RLANE(hpA, kk);
                u32 xB = RLANE(hpB, kk);
                aA[kk & 3] = fdot2f(xA, wh[kk], aA[kk & 3]);
                aB[kk & 3] = fdot2f(xB, wh[kk], aB[kk & 3]);
            }
            float hbA = fmaxf((aA[0]+aA[1]) + (aA[2]+aA[3]) + bc, 0.f);
            float hbB = fmaxf((aB[0]+aB[1]) + (aB[2]+aB[3]) + bc, 0.f);
            runS += hbA + hbB;
            runQ = fmaf(hbA, hbA, runQ);
            runQ = fmaf(hbB, hbB, runQ);
            mh = fmaxf(mh, fmaxf(hbA, hbB));
        }
        if (i < d){
            int sA = epi[2*(r0 + i)];
            f16x2 qA = *(const f16x2*)(PQ1 + (size_t)sA*256 + 128 + 2*lane);
            f16x2 hA = pv + qA;
            hA[0] = hA[0] > z0 ? hA[0] : z0;  hA[1] = hA[1] > z0 ? hA[1] : z0;
            u32 hpA = __builtin_bit_cast(u32, hA);
            float aA[4] = {0.f,0.f,0.f,0.f};
            #pragma unroll
            for (int kk = 0; kk < 64; kk++){
                u32 xA = RLANE(hpA, kk);
                aA[kk & 3] = fdot2f(xA, wh[kk], aA[kk & 3]);
            }
            float hbA = fmaxf((aA[0]+aA[1]) + (aA[2]+aA[3]) + bc, 0.f);
            runS += hbA;
            runQ = fmaf(hbA, hbA, runQ);
            mh = fmaxf(mh, hbA);
        }
        if (d > 0) agg[(size_t)n*64 + lane] = mh;
    }
    __shared__ float bS[256], bQ[256];
    bS[tid] = runS; bQ[tid] = runQ;
    __syncthreads();
    if (wave == 0){
        float s = bS[lane] + bS[64+lane] + bS[128+lane] + bS[192+lane];
        float q = bQ[lane] + bQ[64+lane] + bQ[128+lane] + bQ[192+lane];
        atomicAdd(&pblk[256 + lane], s);
        atomicAdd(&pblk[320 + lane], q);
    }
}

__global__ void k_fold_st(const float* __restrict__ g, const float* __restrict__ bt,
                          float* __restrict__ pblk, float fE, int so, int qo, int os, int ot)
{
    int tid = threadIdx.x;
    if (tid < 64){
        float m = pblk[so + tid] * fE;
        float q = pblk[qo + tid] * fE;
        float v = fmaxf(q - m*m, 0.f);
        float s = g[tid] * rsqrtf(v + EPSBN);
        pblk[os + tid] = s;
        pblk[ot + tid] = bt[tid] - m*s;
    }
}

// x1 = relu(bn1b(agg) or 0) -> x1b; reset agg to -inf for pass3p reuse.
__global__ void k_x1(float* __restrict__ agg, const float* __restrict__ pblk,
                     u16* __restrict__ x1b, int NF)
{
    int i = blockIdx.x*256 + threadIdx.x;
    if (i >= NF) return;
    int c = i & 63;
    float a = agg[i];
    float v = (a > -INFINITY) ? fmaf(a, pblk[832 + c], pblk[896 + c]) : 0.f;
    v = fmaxf(v, 0.f);
    x1b[i] = (u16)f2bf1(v);
    agg[i] = -INFINITY;
}

// pass3p: PULL-based conv2 (R10 verbatim; PQ2 stays bf16).
__global__ __launch_bounds__(256) void k_pass3p(
    const u16* __restrict__ PQ2, const int2* __restrict__ ep,
    const int* __restrict__ cursor, const int* __restrict__ deg,
    float* __restrict__ pblk, float* __restrict__ agg, int N)
{
    int tid = threadIdx.x;
    int lane = tid & 63, wave = tid >> 6;
    float runS = 0.f, runQ = 0.f;
    const int* epi = (const int*)ep;

    for (int n = blockIdx.x*4 + wave; n < N; n += gridDim.x*4){
        int d  = deg[n];
        int r0 = cursor[n] - d;
        float p = bf2f(PQ2[(size_t)n*128 + lane]);
        float mq = -INFINITY;
        int src = (d > 0) ? epi[2*r0] : 0;
        for (int i = 0; i < d; ++i){
            int srcn = (i + 1 < d) ? epi[2*(r0 + i + 1)] : 0;
            float q = bf2f(PQ2[(size_t)src*128 + 64 + lane]);
            mq = fmaxf(mq, q);
            float h = fmaxf(p + q, 0.f);
            runS += h;
            runQ = fmaf(h, h, runQ);
            src = srcn;
        }
        if (d > 0) agg[(size_t)n*64 + lane] = mq;
    }
    __shared__ float bS[256], bQ[256];
    bS[tid] = runS; bQ[tid] = runQ;
    __syncthreads();
    if (wave == 0){
        float s = bS[lane] + bS[64 + lane] + bS[128 + lane] + bS[192 + lane];
        float q = bQ[lane] + bQ[64 + lane] + bQ[128 + lane] + bQ[192 + lane];
        atomicAdd(&pblk[384 + lane], s);
        atomicAdd(&pblk[448 + lane], q);
    }
}

#define FUSE_NODES 128
__global__ __launch_bounds__(256) void k_fuse(const float* __restrict__ agg,
                                              const u16* __restrict__ x1b,
                                              const u16* __restrict__ PQ2,
                                              const int* __restrict__ batch,
                                              float* __restrict__ pblk, int N)
{
    int c = threadIdx.x & 63, r = threadIdx.x >> 6;
    int n0 = blockIdx.x*FUSE_NODES + r*(FUSE_NODES/4);
    if (n0 >= N) return;
    int n1 = n0 + FUSE_NODES/4; if (n1 > N) n1 = N;
    float s2c = pblk[960 + c], t2c = pblk[1024 + c];
    float gm = -INFINITY, gs = 0.f;
    int cur = batch[n0], cnt0 = 0;
    for (int n = n0; n < n1; ++n){
        int g = batch[n];
        if (g != cur){
            atomicMaxF(&pblk[1088 + cur*64 + c], gm);
            atomicAdd(&pblk[5184 + cur*64 + c], gs);
            if (c == 0) atomicAdd(&pblk[9280 + cur], (float)cnt0);
            gm = -INFINITY; gs = 0.f; cnt0 = 0; cur = g;
        }
        float a = agg[(size_t)n*64 + c];   // maxQ2 (or -inf if no in-edges)
        float v;
        if (a > -INFINITY){
            float p = bf2f(PQ2[(size_t)n*128 + c]);
            float pre = fmaxf(p + a, 0.f);
            v = fmaxf(fmaf(pre, s2c, t2c), 0.f);
        } else v = 0.f;
        float f = bf2f(x1b[(size_t)n*64 + c]) + v;
        gm = fmaxf(gm, f); gs += f; cnt0++;
    }
    atomicMaxF(&pblk[1088 + cur*64 + c], gm);
    atomicAdd(&pblk[5184 + cur*64 + c], gs);
    if (c == 0) atomicAdd(&pblk[9280 + cur], (float)cnt0);
}

__global__ void k_out(const float* __restrict__ pblk, float* __restrict__ out)
{
    int i = blockIdx.x*256 + threadIdx.x;
    if (i >= 64*128) return;
    int g = i >> 7, c = i & 127;
    float r;
    if (c < 64){
        float m = pblk[1088 + g*64 + c];
        r = (m > -INFINITY) ? m : 0.f;
    } else {
        float s = pblk[5184 + g*64 + (c - 64)];
        float n = pblk[9280 + g];
        r = s / fmaxf(n, 1.f);
    }
    out[i] = r;
}

extern "C" void kernel_launch(void* const* d_in, const int* in_sizes, int n_in,
                              void* d_out, int out_size, void* d_ws, size_t ws_size,
                              hipStream_t stream)
{
    const float* x    = (const float*)d_in[0];
    const int*   ei   = (const int*)  d_in[1];
    const int*   batch= (const int*)  d_in[2];
    const float* W1a  = (const float*)d_in[3];
    const float* b1a  = (const float*)d_in[4];
    const float* g1a  = (const float*)d_in[5];
    const float* bt1a = (const float*)d_in[6];
    const float* W1b  = (const float*)d_in[7];
    const float* b1b  = (const float*)d_in[8];
    const float* g1b  = (const float*)d_in[9];
    const float* bt1b = (const float*)d_in[10];
    const float* W2   = (const float*)d_in[11];
    const float* b2   = (const float*)d_in[12];
    const float* g2   = (const float*)d_in[13];
    const float* bt2  = (const float*)d_in[14];

    int N  = in_sizes[0] / 64;
    int E  = in_sizes[1] / 2;
    int NF = N * 64;

    char* ws = (char*)d_ws;
    size_t off = 0;
    auto alloc = [&](size_t bytes){ size_t o = off; off += (bytes + 255) & ~(size_t)255; return o; };
    u16*   xb    = (u16*)  (ws + alloc((size_t)NF*2));
    u16*   x1b   = (u16*)  (ws + alloc((size_t)NF*2));
    float* agg   = (float*)(ws + alloc((size_t)NF*4));
    float* pblk  = (float*)(ws + alloc((size_t)PB_TOT*4));
    int*   deg   = (int*)  (ws + alloc((size_t)N*4));
    int*   cursor= (int*)  (ws + alloc((size_t)N*4));
    int2*  ep    = (int2*) (ws + alloc((size_t)E*8));
    u16*   PQ1   = (u16*)  (ws + alloc((size_t)N*256*2));
    u16*   PQ2   = (u16*)  (ws + alloc((size_t)N*128*2));
    (void)ws_size;   // ~71MB << proven 237.7MB budget

    const int* esrc = ei;
    const int* edst = ei + E;
    int gElem  = (NF + 255) / 256;
    int gEdge  = (E + 255) / 256;
    int gNode  = (N + 63) / 64;
    int gPull  = ((N + 3) / 4) < 2048 ? ((N + 3) / 4) : 2048;
    float fE   = 1.f / (float)E;

    k_init        <<<gElem, 256, 0, stream>>>(x, xb, agg, pblk, deg, NF, N);
    k_hist        <<<gEdge, 256, 0, stream>>>(edst, deg, E);
    k_scan        <<<1, 1024, 0, stream>>>(deg, cursor, N);
    k_scatter     <<<gEdge, 256, 0, stream>>>(esrc, edst, cursor, ep, E);
    k_ngemm<256,1><<<gNode, 256, 0, stream>>>(xb, W1a, b1a, PQ1, N);
    k_pass1p      <<<gPull, 256, 0, stream>>>(PQ1, ep, cursor, deg, pblk, N);
    k_fold1       <<<1, 128, 0, stream>>>(g1a, bt1a, W1b, b1b, pblk, fE);
    k_pass2p      <<<gPull, 256, 0, stream>>>(PQ1, ep, cursor, deg, W1b, pblk, agg, N);
    k_fold_st     <<<1, 64, 0, stream>>>(g1b, bt1b, pblk, fE, 256, 320, 832, 896);
    k_x1          <<<gElem, 256, 0, stream>>>(agg, pblk, x1b, NF);
    k_ngemm<128,0><<<gNode, 256, 0, stream>>>(x1b, W2, b2, PQ2, N);
    k_pass3p      <<<gPull, 256, 0, stream>>>(PQ2, ep, cursor, deg, pblk, agg, N);
    k_fold_st     <<<1, 64, 0, stream>>>(g2, bt2, pblk, fE, 384, 448, 960, 1024);
    k_fuse        <<<(N + FUSE_NODES - 1)/FUSE_NODES, 256, 0, stream>>>(agg, x1b, PQ2, batch, pblk, N);
    k_out         <<<32, 256, 0, stream>>>(pblk, (float*)d_out);
}

// Round 16
// 740.471 us; speedup vs baseline: 2.8633x; 1.1749x over previous
//
#include <hip/hip_runtime.h>
#include <math.h>

// GraphNet: 2x EdgeConv (E=800k, F=H=64) + BN folded/commuted + pooling.
// R16: supporting-cast cleanup around the proven pull pipeline (R15 870us):
//  - k_scan (single-block, ~49 serial barrier-iterations on 1 CU) -> 3-kernel
//    parallel scan (partial/offsets/add).
//  - pass1p/pass3p get 2-edge ILP (R14 lesson: serial gather chains stall).
//  - ep int2 -> eps int (sorted src only; dst is implicit in pull kernels).
//  - FUSE_NODES 128->32 (k_fuse was 1.5 blocks/CU).
// pass2p (readlane+fdot2, 287us @ 68% VALU) unchanged.

typedef unsigned short u16;
typedef unsigned int   u32;
typedef __bf16 bf16x8 __attribute__((ext_vector_type(8)));
typedef float  f32x4  __attribute__((ext_vector_type(4)));
typedef unsigned short us4 __attribute__((ext_vector_type(4)));
typedef _Float16 f16;
typedef f16 f16x2 __attribute__((ext_vector_type(2)));

#define EPSBN 1e-5f
#define PB_TOT 9344
// pblk: 0:stS1a[128] 128:stQ1a[128] 256:stS1b 320:stQ1b 384:stS2 448:stQ2
// 512:s1a[128] 640:t1a[128] 768:b1bF[64] 832:s1b 896:t1b 960:s2 1024:t2
// 1088:gmax[4096] 5184:gsum[4096] 9280:cnt[64]

#if __has_builtin(__builtin_amdgcn_fdot2)
#define HAS_FDOT2 1
#else
#define HAS_FDOT2 0
#endif
#if __has_builtin(__builtin_amdgcn_readlane)
#define RLANE(v, l) ((u32)__builtin_amdgcn_readlane((int)(v), (l)))
#else
#define RLANE(v, l) ((u32)__shfl((int)(v), (l), 64))
#endif

__device__ __forceinline__ u32 f2bf1(float f){
    u32 u = __float_as_uint(f);
    return (u + 0x7FFFu + ((u >> 16) & 1u)) >> 16;
}
__device__ __forceinline__ float bf2f(u16 b){
    return __uint_as_float(((u32)b) << 16);
}
__device__ __forceinline__ void atomicMaxF(float* a, float v){
    if (v >= 0.f) atomicMax((int*)a, __float_as_int(v));
    else          atomicMin((u32*)a, __float_as_uint(v));
}
__device__ __forceinline__ int swz64(int row, int k){
    return row*64 + (k ^ ((row & 7) << 3));
}
__device__ __forceinline__ f32x4 mfma16(bf16x8 a, bf16x8 b, f32x4 c){
    return __builtin_amdgcn_mfma_f32_16x16x32_bf16(a, b, c, 0, 0, 0);
}
__device__ __forceinline__ float fdot2f(u32 h, f16x2 w, float acc){
#if HAS_FDOT2
    return __builtin_amdgcn_fdot2(__builtin_bit_cast(f16x2, h), w, acc, false);
#else
    f16x2 hh = __builtin_bit_cast(f16x2, h);
    acc = fmaf((float)hh[0], (float)w[0], acc);
    return fmaf((float)hh[1], (float)w[1], acc);
#endif
}

__global__ void k_init(const float* __restrict__ x, u16* __restrict__ xb,
                       float* __restrict__ agg,
                       float* __restrict__ pblk, int* __restrict__ deg,
                       int NF, int N){
    int i = blockIdx.x*256 + threadIdx.x;
    if (i < NF){
        xb[i] = (u16)f2bf1(x[i]);
        agg[i] = -INFINITY;
    }
    if (i < N) deg[i] = 0;
    if (i < PB_TOT){
        pblk[i] = (i >= 1088 && i < 5184) ? -INFINITY : 0.f;
    }
}

__global__ void k_hist(const int* __restrict__ edst, int* __restrict__ deg, int E){
    int e = blockIdx.x*256 + threadIdx.x;
    if (e < E) atomicAdd(&deg[edst[e]], 1);
}

// 3-kernel parallel exclusive scan of deg -> cursor.
__global__ __launch_bounds__(1024) void k_scanA(const int* __restrict__ deg,
                                                int* __restrict__ cursor,
                                                int* __restrict__ bsum, int N){
    __shared__ int buf[1024];
    int tid = threadIdx.x;
    int i = blockIdx.x*1024 + tid;
    int v = (i < N) ? deg[i] : 0;
    buf[tid] = v;
    __syncthreads();
    #pragma unroll
    for (int s = 1; s < 1024; s <<= 1){
        int a = (tid >= s) ? buf[tid - s] : 0;
        __syncthreads();
        buf[tid] += a;
        __syncthreads();
    }
    if (i < N) cursor[i] = buf[tid] - v;   // block-local exclusive
    if (tid == 1023) bsum[blockIdx.x] = buf[1023];
}
__global__ void k_scanB(const int* __restrict__ bsum, int* __restrict__ boff, int nblk){
    if (threadIdx.x == 0){
        int run = 0;
        for (int i = 0; i < nblk; ++i){ boff[i] = run; run += bsum[i]; }
    }
}
__global__ __launch_bounds__(1024) void k_scanC(int* __restrict__ cursor,
                                                const int* __restrict__ boff, int N){
    int i = blockIdx.x*1024 + threadIdx.x;
    if (i < N) cursor[i] += boff[blockIdx.x];
}

// counting-sort scatter: only the src index is needed downstream (dst == row).
__global__ void k_scatter(const int* __restrict__ esrc, const int* __restrict__ edst,
                          int* __restrict__ cursor, int* __restrict__ eps, int E){
    int e = blockIdx.x*256 + threadIdx.x;
    if (e < E){
        int d = edst[e];
        int pos = atomicAdd(&cursor[d], 1);
        eps[pos] = esrc[e];
    }
}

// Node GEMM -> PQ table. FMT=0: bf16 out; FMT=1: f16 out.
template<int COUT, int FMT>
__global__ __launch_bounds__(256) void k_ngemm(
    const u16* __restrict__ xin, const float* __restrict__ Wsrc,
    const float* __restrict__ bias, u16* __restrict__ PQ, int N)
{
    const int WC = COUT/2;
    __shared__ u16 Wt[COUT*64];
    __shared__ u16 At[64*64];
    int tid = threadIdx.x;
    for (int i = tid; i < COUT*64; i += 256){
        int c = i >> 6, k = i & 63;
        float w = (c < WC) ? (Wsrc[k*WC + c] - Wsrc[(64+k)*WC + c])
                           : Wsrc[(64+k)*WC + (c - WC)];
        Wt[swz64(c, k)] = (u16)f2bf1(w);
    }
    int t = blockIdx.x;
    for (int i = tid; i < 512; i += 256){
        int row = i >> 3, ck = i & 7;
        int node = t*64 + row;
        uint4 v;
        if (node < N) v = *(const uint4*)(xin + (size_t)node*64 + ck*8);
        else { v.x = v.y = v.z = v.w = 0u; }
        *(uint4*)&At[swz64(row, ck*8)] = v;
    }
    __syncthreads();
    int lane = tid & 63, wave = tid >> 6;
    int lg = lane >> 4, lr = lane & 15;
    int row = wave*16 + lr;
    bf16x8 bfr[2];
    #pragma unroll
    for (int kt = 0; kt < 2; kt++)
        bfr[kt] = *(const bf16x8*)&At[swz64(row, kt*32 + lg*8)];
    int node = t*64 + wave*16 + lr;
    #pragma unroll
    for (int mt = 0; mt < COUT/16; mt++){
        f32x4 acc = {0.f,0.f,0.f,0.f};
        #pragma unroll
        for (int kt = 0; kt < 2; kt++){
            bf16x8 af = *(const bf16x8*)&Wt[swz64(mt*16 + lr, kt*32 + lg*8)];
            acc = mfma16(af, bfr[kt], acc);
        }
        int ch = mt*16 + lg*4;
        float r[4] = {acc[0], acc[1], acc[2], acc[3]};
        if (ch < WC){
            float4 bb = *(const float4*)(bias + ch);
            r[0] += bb.x; r[1] += bb.y; r[2] += bb.z; r[3] += bb.w;
        }
        if (node < N){
            us4 w4;
            #pragma unroll
            for (int j = 0; j < 4; j++){
                if (FMT){
                    f16 hf = (f16)r[j];
                    w4[j] = __builtin_bit_cast(u16, hf);
                } else {
                    w4[j] = (u16)f2bf1(r[j]);
                }
            }
            *(us4*)(PQ + (size_t)node*COUT + ch) = w4;
        }
    }
}

// pass1p: pull BN1a stats from f16 PQ1; 2 edges/iter (2 loads in flight).
__global__ __launch_bounds__(256) void k_pass1p(
    const u16* __restrict__ PQ1, const int* __restrict__ eps,
    const int* __restrict__ cursor, const int* __restrict__ deg,
    float* __restrict__ pblk, int N)
{
    int tid = threadIdx.x;
    int lane = tid & 63, wave = tid >> 6;
    float s0 = 0.f, s1 = 0.f, q0 = 0.f, q1 = 0.f;

    for (int n = blockIdx.x*4 + wave; n < N; n += gridDim.x*4){
        int d  = deg[n];
        int r0 = cursor[n] - d;
        f16x2 pv = *(const f16x2*)(PQ1 + (size_t)n*256 + 2*lane);
        int i = 0;
        for (; i + 1 < d; i += 2){
            int sA = eps[r0 + i];
            int sB = eps[r0 + i + 1];
            f16x2 qA = *(const f16x2*)(PQ1 + (size_t)sA*256 + 128 + 2*lane);
            f16x2 qB = *(const f16x2*)(PQ1 + (size_t)sB*256 + 128 + 2*lane);
            f16x2 hA = pv + qA, hB = pv + qB;
            float a0 = fmaxf((float)hA[0], 0.f), a1 = fmaxf((float)hA[1], 0.f);
            float b0 = fmaxf((float)hB[0], 0.f), b1 = fmaxf((float)hB[1], 0.f);
            s0 += a0 + b0; s1 += a1 + b1;
            q0 = fmaf(a0, a0, q0); q0 = fmaf(b0, b0, q0);
            q1 = fmaf(a1, a1, q1); q1 = fmaf(b1, b1, q1);
        }
        if (i < d){
            int sA = eps[r0 + i];
            f16x2 qA = *(const f16x2*)(PQ1 + (size_t)sA*256 + 128 + 2*lane);
            f16x2 hA = pv + qA;
            float a0 = fmaxf((float)hA[0], 0.f), a1 = fmaxf((float)hA[1], 0.f);
            s0 += a0; s1 += a1;
            q0 = fmaf(a0, a0, q0);
            q1 = fmaf(a1, a1, q1);
        }
    }
    __shared__ float bS0[256], bS1[256], bQ0[256], bQ1[256];
    bS0[tid] = s0; bS1[tid] = s1; bQ0[tid] = q0; bQ1[tid] = q1;
    __syncthreads();
    if (wave == 0){
        float a0 = bS0[lane] + bS0[64+lane] + bS0[128+lane] + bS0[192+lane];
        float a1 = bS1[lane] + bS1[64+lane] + bS1[128+lane] + bS1[192+lane];
        float c0 = bQ0[lane] + bQ0[64+lane] + bQ0[128+lane] + bQ0[192+lane];
        float c1 = bQ1[lane] + bQ1[64+lane] + bQ1[128+lane] + bQ1[192+lane];
        atomicAdd(&pblk[2*lane],       a0);
        atomicAdd(&pblk[2*lane + 1],   a1);
        atomicAdd(&pblk[128 + 2*lane],     c0);
        atomicAdd(&pblk[128 + 2*lane + 1], c1);
    }
}

__global__ void k_fold1(const float* __restrict__ g1a, const float* __restrict__ bt1a,
                        const float* __restrict__ W1b, const float* __restrict__ b1b,
                        float* __restrict__ pblk, float fE)
{
    __shared__ float tS[128];
    int tid = threadIdx.x;
    if (tid < 128){
        float m = pblk[tid] * fE;
        float q = pblk[128 + tid] * fE;
        float v = fmaxf(q - m*m, 0.f);
        float s = g1a[tid] * rsqrtf(v + EPSBN);
        float t = bt1a[tid] - m*s;
        pblk[512 + tid] = s;
        pblk[640 + tid] = t;
        tS[tid] = t;
    }
    __syncthreads();
    if (tid < 64){
        float acc = b1b[tid];
        for (int k = 0; k < 128; k++) acc = fmaf(tS[k], W1b[k*64 + tid], acc);
        pblk[768 + tid] = acc;
    }
}

// pass2p: pull GEMM-b, 2 edges/iter x 4 accumulators; readlane + fdot2.
__global__ __launch_bounds__(256) void k_pass2p(
    const u16* __restrict__ PQ1, const int* __restrict__ eps,
    const int* __restrict__ cursor, const int* __restrict__ deg,
    const float* __restrict__ W1b,
    float* __restrict__ pblk, float* __restrict__ agg, int N)
{
    int tid = threadIdx.x;
    int lane = tid & 63, wave = tid >> 6;
    f16x2 wh[64];
    #pragma unroll
    for (int kk = 0; kk < 64; kk++){
        float w0 = pblk[512 + 2*kk]     * W1b[(2*kk)*64 + lane];
        float w1 = pblk[512 + 2*kk + 1] * W1b[(2*kk + 1)*64 + lane];
        f16x2 t; t[0] = (f16)w0; t[1] = (f16)w1;
        wh[kk] = t;
    }
    float bc = pblk[768 + lane];
    float runS = 0.f, runQ = 0.f;
    const f16 z0 = (f16)0;

    for (int n = blockIdx.x*4 + wave; n < N; n += gridDim.x*4){
        int d  = deg[n];
        int r0 = cursor[n] - d;
        f16x2 pv = *(const f16x2*)(PQ1 + (size_t)n*256 + 2*lane);
        float mh = -INFINITY;
        int i = 0;
        for (; i + 1 < d; i += 2){
            int sA = eps[r0 + i];
            int sB = eps[r0 + i + 1];
            f16x2 qA = *(const f16x2*)(PQ1 + (size_t)sA*256 + 128 + 2*lane);
            f16x2 qB = *(const f16x2*)(PQ1 + (size_t)sB*256 + 128 + 2*lane);
            f16x2 hA = pv + qA, hB = pv + qB;
            hA[0] = hA[0] > z0 ? hA[0] : z0;  hA[1] = hA[1] > z0 ? hA[1] : z0;
            hB[0] = hB[0] > z0 ? hB[0] : z0;  hB[1] = hB[1] > z0 ? hB[1] : z0;
            u32 hpA = __builtin_bit_cast(u32, hA);
            u32 hpB = __builtin_bit_cast(u32, hB);
            float aA[4] = {0.f,0.f,0.f,0.f};
            float aB[4] = {0.f,0.f,0.f,0.f};
            #pragma unroll
            for (int kk = 0; kk < 64; kk++){
                u32 xA = RLANE(hpA, kk);
                u32 xB = RLANE(hpB, kk);
                aA[kk & 3] = fdot2f(xA, wh[kk], aA[kk & 3]);
                aB[kk & 3] = fdot2f(xB, wh[kk], aB[kk & 3]);
            }
            float hbA = fmaxf((aA[0]+aA[1]) + (aA[2]+aA[3]) + bc, 0.f);
            float hbB = fmaxf((aB[0]+aB[1]) + (aB[2]+aB[3]) + bc, 0.f);
            runS += hbA + hbB;
            runQ = fmaf(hbA, hbA, runQ);
            runQ = fmaf(hbB, hbB, runQ);
            mh = fmaxf(mh, fmaxf(hbA, hbB));
        }
        if (i < d){
            int sA = eps[r0 + i];
            f16x2 qA = *(const f16x2*)(PQ1 + (size_t)sA*256 + 128 + 2*lane);
            f16x2 hA = pv + qA;
            hA[0] = hA[0] > z0 ? hA[0] : z0;  hA[1] = hA[1] > z0 ? hA[1] : z0;
            u32 hpA = __builtin_bit_cast(u32, hA);
            float aA[4] = {0.f,0.f,0.f,0.f};
            #pragma unroll
            for (int kk = 0; kk < 64; kk++){
                u32 xA = RLANE(hpA, kk);
                aA[kk & 3] = fdot2f(xA, wh[kk], aA[kk & 3]);
            }
            float hbA = fmaxf((aA[0]+aA[1]) + (aA[2]+aA[3]) + bc, 0.f);
            runS += hbA;
            runQ = fmaf(hbA, hbA, runQ);
            mh = fmaxf(mh, hbA);
        }
        if (d > 0) agg[(size_t)n*64 + lane] = mh;
    }
    __shared__ float bS[256], bQ[256];
    bS[tid] = runS; bQ[tid] = runQ;
    __syncthreads();
    if (wave == 0){
        float s = bS[lane] + bS[64+lane] + bS[128+lane] + bS[192+lane];
        float q = bQ[lane] + bQ[64+lane] + bQ[128+lane] + bQ[192+lane];
        atomicAdd(&pblk[256 + lane], s);
        atomicAdd(&pblk[320 + lane], q);
    }
}

__global__ void k_fold_st(const float* __restrict__ g, const float* __restrict__ bt,
                          float* __restrict__ pblk, float fE, int so, int qo, int os, int ot)
{
    int tid = threadIdx.x;
    if (tid < 64){
        float m = pblk[so + tid] * fE;
        float q = pblk[qo + tid] * fE;
        float v = fmaxf(q - m*m, 0.f);
        float s = g[tid] * rsqrtf(v + EPSBN);
        pblk[os + tid] = s;
        pblk[ot + tid] = bt[tid] - m*s;
    }
}

// x1 = relu(bn1b(agg) or 0) -> x1b; reset agg to -inf for pass3p reuse.
__global__ void k_x1(float* __restrict__ agg, const float* __restrict__ pblk,
                     u16* __restrict__ x1b, int NF)
{
    int i = blockIdx.x*256 + threadIdx.x;
    if (i >= NF) return;
    int c = i & 63;
    float a = agg[i];
    float v = (a > -INFINITY) ? fmaf(a, pblk[832 + c], pblk[896 + c]) : 0.f;
    v = fmaxf(v, 0.f);
    x1b[i] = (u16)f2bf1(v);
    agg[i] = -INFINITY;
}

// pass3p: pull conv2 (stats2 + segmax Q2), 2 edges/iter.
__global__ __launch_bounds__(256) void k_pass3p(
    const u16* __restrict__ PQ2, const int* __restrict__ eps,
    const int* __restrict__ cursor, const int* __restrict__ deg,
    float* __restrict__ pblk, float* __restrict__ agg, int N)
{
    int tid = threadIdx.x;
    int lane = tid & 63, wave = tid >> 6;
    float runS = 0.f, runQ = 0.f;

    for (int n = blockIdx.x*4 + wave; n < N; n += gridDim.x*4){
        int d  = deg[n];
        int r0 = cursor[n] - d;
        float p = bf2f(PQ2[(size_t)n*128 + lane]);
        float mq = -INFINITY;
        int i = 0;
        for (; i + 1 < d; i += 2){
            int sA = eps[r0 + i];
            int sB = eps[r0 + i + 1];
            float qA = bf2f(PQ2[(size_t)sA*128 + 64 + lane]);
            float qB = bf2f(PQ2[(size_t)sB*128 + 64 + lane]);
            mq = fmaxf(mq, fmaxf(qA, qB));
            float hA = fmaxf(p + qA, 0.f);
            float hB = fmaxf(p + qB, 0.f);
            runS += hA + hB;
            runQ = fmaf(hA, hA, runQ);
            runQ = fmaf(hB, hB, runQ);
        }
        if (i < d){
            int sA = eps[r0 + i];
            float qA = bf2f(PQ2[(size_t)sA*128 + 64 + lane]);
            mq = fmaxf(mq, qA);
            float hA = fmaxf(p + qA, 0.f);
            runS += hA;
            runQ = fmaf(hA, hA, runQ);
        }
        if (d > 0) agg[(size_t)n*64 + lane] = mq;
    }
    __shared__ float bS[256], bQ[256];
    bS[tid] = runS; bQ[tid] = runQ;
    __syncthreads();
    if (wave == 0){
        float s = bS[lane] + bS[64 + lane] + bS[128 + lane] + bS[192 + lane];
        float q = bQ[lane] + bQ[64 + lane] + bQ[128 + lane] + bQ[192 + lane];
        atomicAdd(&pblk[384 + lane], s);
        atomicAdd(&pblk[448 + lane], q);
    }
}

#define FUSE_NODES 32
__global__ __launch_bounds__(256) void k_fuse(const float* __restrict__ agg,
                                              const u16* __restrict__ x1b,
                                              const u16* __restrict__ PQ2,
                                              const int* __restrict__ batch,
                                              float* __restrict__ pblk, int N)
{
    int c = threadIdx.x & 63, r = threadIdx.x >> 6;
    int n0 = blockIdx.x*FUSE_NODES + r*(FUSE_NODES/4);
    if (n0 >= N) return;
    int n1 = n0 + FUSE_NODES/4; if (n1 > N) n1 = N;
    float s2c = pblk[960 + c], t2c = pblk[1024 + c];
    float gm = -INFINITY, gs = 0.f;
    int cur = batch[n0], cnt0 = 0;
    for (int n = n0; n < n1; ++n){
        int g = batch[n];
        if (g != cur){
            atomicMaxF(&pblk[1088 + cur*64 + c], gm);
            atomicAdd(&pblk[5184 + cur*64 + c], gs);
            if (c == 0) atomicAdd(&pblk[9280 + cur], (float)cnt0);
            gm = -INFINITY; gs = 0.f; cnt0 = 0; cur = g;
        }
        float a = agg[(size_t)n*64 + c];   // maxQ2 (or -inf if no in-edges)
        float v;
        if (a > -INFINITY){
            float p = bf2f(PQ2[(size_t)n*128 + c]);
            float pre = fmaxf(p + a, 0.f);
            v = fmaxf(fmaf(pre, s2c, t2c), 0.f);
        } else v = 0.f;
        float f = bf2f(x1b[(size_t)n*64 + c]) + v;
        gm = fmaxf(gm, f); gs += f; cnt0++;
    }
    atomicMaxF(&pblk[1088 + cur*64 + c], gm);
    atomicAdd(&pblk[5184 + cur*64 + c], gs);
    if (c == 0) atomicAdd(&pblk[9280 + cur], (float)cnt0);
}

__global__ void k_out(const float* __restrict__ pblk, float* __restrict__ out)
{
    int i = blockIdx.x*256 + threadIdx.x;
    if (i >= 64*128) return;
    int g = i >> 7, c = i & 127;
    float r;
    if (c < 64){
        float m = pblk[1088 + g*64 + c];
        r = (m > -INFINITY) ? m : 0.f;
    } else {
        float s = pblk[5184 + g*64 + (c - 64)];
        float n = pblk[9280 + g];
        r = s / fmaxf(n, 1.f);
    }
    out[i] = r;
}

extern "C" void kernel_launch(void* const* d_in, const int* in_sizes, int n_in,
                              void* d_out, int out_size, void* d_ws, size_t ws_size,
                              hipStream_t stream)
{
    const float* x    = (const float*)d_in[0];
    const int*   ei   = (const int*)  d_in[1];
    const int*   batch= (const int*)  d_in[2];
    const float* W1a  = (const float*)d_in[3];
    const float* b1a  = (const float*)d_in[4];
    const float* g1a  = (const float*)d_in[5];
    const float* bt1a = (const float*)d_in[6];
    const float* W1b  = (const float*)d_in[7];
    const float* b1b  = (const float*)d_in[8];
    const float* g1b  = (const float*)d_in[9];
    const float* bt1b = (const float*)d_in[10];
    const float* W2   = (const float*)d_in[11];
    const float* b2   = (const float*)d_in[12];
    const float* g2   = (const float*)d_in[13];
    const float* bt2  = (const float*)d_in[14];

    int N  = in_sizes[0] / 64;
    int E  = in_sizes[1] / 2;
    int NF = N * 64;

    char* ws = (char*)d_ws;
    size_t off = 0;
    auto alloc = [&](size_t bytes){ size_t o = off; off += (bytes + 255) & ~(size_t)255; return o; };
    u16*   xb    = (u16*)  (ws + alloc((size_t)NF*2));
    u16*   x1b   = (u16*)  (ws + alloc((size_t)NF*2));
    float* agg   = (float*)(ws + alloc((size_t)NF*4));
    float* pblk  = (float*)(ws + alloc((size_t)PB_TOT*4));
    int*   deg   = (int*)  (ws + alloc((size_t)N*4));
    int*   cursor= (int*)  (ws + alloc((size_t)N*4));
    int*   eps   = (int*)  (ws + alloc((size_t)E*4));
    u16*   PQ1   = (u16*)  (ws + alloc((size_t)N*256*2));
    u16*   PQ2   = (u16*)  (ws + alloc((size_t)N*128*2));
    int*   bsum  = (int*)  (ws + alloc((size_t)1024*4));
    int*   boff  = (int*)  (ws + alloc((size_t)1024*4));
    (void)ws_size;   // ~68MB << proven 237.7MB budget

    const int* esrc = ei;
    const int* edst = ei + E;
    int gElem  = (NF + 255) / 256;
    int gEdge  = (E + 255) / 256;
    int gNode  = (N + 63) / 64;
    int gScan  = (N + 1023) / 1024;
    int gPull  = ((N + 3) / 4) < 2048 ? ((N + 3) / 4) : 2048;
    float fE   = 1.f / (float)E;

    k_init        <<<gElem, 256, 0, stream>>>(x, xb, agg, pblk, deg, NF, N);
    k_hist        <<<gEdge, 256, 0, stream>>>(edst, deg, E);
    k_scanA       <<<gScan, 1024, 0, stream>>>(deg, cursor, bsum, N);
    k_scanB       <<<1, 64, 0, stream>>>(bsum, boff, gScan);
    k_scanC       <<<gScan, 1024, 0, stream>>>(cursor, boff, N);
    k_scatter     <<<gEdge, 256, 0, stream>>>(esrc, edst, cursor, eps, E);
    k_ngemm<256,1><<<gNode, 256, 0, stream>>>(xb, W1a, b1a, PQ1, N);
    k_pass1p      <<<gPull, 256, 0, stream>>>(PQ1, eps, cursor, deg, pblk, N);
    k_fold1       <<<1, 128, 0, stream>>>(g1a, bt1a, W1b, b1b, pblk, fE);
    k_pass2p      <<<gPull, 256, 0, stream>>>(PQ1, eps, cursor, deg, W1b, pblk, agg, N);
    k_fold_st     <<<1, 64, 0, stream>>>(g1b, bt1b, pblk, fE, 256, 320, 832, 896);
    k_x1          <<<gElem, 256, 0, stream>>>(agg, pblk, x1b, NF);
    k_ngemm<128,0><<<gNode, 256, 0, stream>>>(x1b, W2, b2, PQ2, N);
    k_pass3p      <<<gPull, 256, 0, stream>>>(PQ2, eps, cursor, deg, pblk, agg, N);
    k_fold_st     <<<1, 64, 0, stream>>>(g2, bt2, pblk, fE, 384, 448, 960, 1024);
    k_fuse        <<<(N + FUSE_NODES - 1)/FUSE_NODES, 256, 0, stream>>>(agg, x1b, PQ2, batch, pblk, N);
    k_out         <<<32, 256, 0, stream>>>(pblk, (float*)d_out);
}